// Round 1
// baseline (1486.285 us; speedup 1.0000x reference)
//
#include <hip/hip_runtime.h>

#define CDIV(a,b) (((a)+(b)-1)/(b))

// ---------------------------------------------------------------------------
// K1: per-original-edge degree count + edge_attr sum (for self-loop fill)
__global__ void k_deg(const int* __restrict__ ei, const float* __restrict__ ea,
                      float* __restrict__ deg, float* __restrict__ lsum, int E) {
    int e = blockIdx.x * 256 + threadIdx.x;
    if (e >= E) return;
    int d = ei[E + e];
    atomicAdd(&deg[d], 1.0f);
    atomicAdd(&lsum[d], ea[e]);
}

// K2: loop_attr[n] = lsum[n] / max(deg[n], 1)   (in place on lsum)
__global__ void k_loopattr(float* __restrict__ lsum, const float* __restrict__ deg, int n) {
    int i = blockIdx.x * 256 + threadIdx.x;
    if (i >= n) return;
    lsum[i] = lsum[i] / fmaxf(deg[i], 1.0f);
}

// K3: exclusive scan of (deg[n]+1) -> off[0..n], single block of 1024 threads
__global__ void k_scan(const float* __restrict__ deg, int* __restrict__ off, int n) {
    __shared__ int part[1024];
    int t = threadIdx.x;
    int chunk = (n + 1023) / 1024;
    int s0 = t * chunk;
    int s1 = s0 + chunk; if (s1 > n) s1 = n; if (s0 > n) s0 = n;
    int s = 0;
    for (int i = s0; i < s1; ++i) s += (int)deg[i] + 1;
    part[t] = s;
    __syncthreads();
    for (int d = 1; d < 1024; d <<= 1) {
        int v = (t >= d) ? part[t - d] : 0;
        __syncthreads();
        part[t] += v;
        __syncthreads();
    }
    int excl = (t == 0) ? 0 : part[t - 1];
    for (int i = s0; i < s1; ++i) { off[i] = excl; excl += (int)deg[i] + 1; }
    if (t == 1023) off[n] = excl;
}

// K4: CSR fill over extended edges (E originals + n self loops)
__global__ void k_fill(const int* __restrict__ ei, const float* __restrict__ ea,
                       const float* __restrict__ lattr, const int* __restrict__ off,
                       int* __restrict__ cursor, int* __restrict__ csr_src,
                       float* __restrict__ csr_ea, int E, int n) {
    int e = blockIdx.x * 256 + threadIdx.x;
    int EE = E + n;
    if (e >= EE) return;
    int s, d; float a;
    if (e < E) { s = ei[e]; d = ei[E + e]; a = ea[e]; }
    else       { s = e - E; d = s;         a = lattr[s]; }
    int pos = off[d] + atomicAdd(&cursor[d], 1);
    csr_src[pos] = s;
    csr_ea[pos] = a;
}

// K5: encoder  h0[n,64] = relu(x[n,:4] @ enc_w + enc_b)
__global__ void k_enc(const float* __restrict__ x, const float* __restrict__ w,
                      const float* __restrict__ b, float* __restrict__ h0, int n) {
    int idx = blockIdx.x * 256 + threadIdx.x;
    if (idx >= n * 64) return;
    int nn = idx >> 6, j = idx & 63;
    const float* xr = x + (size_t)nn * 4;
    float s = b[j];
#pragma unroll
    for (int k = 0; k < 4; ++k) s = fmaf(xr[k], w[k * 64 + j], s);
    h0[idx] = fmaxf(s, 0.0f);
}

// K6: GEMM  C[r,j] = sum_k H[r,k] W[k,j] + b[j];  cols fixed at 256.
// 256 threads = 256 cols; 16 rows per block. H row elements are block-uniform
// -> compiler emits scalar (s_load) for them; W loads coalesced across j.
__global__ void k_gemm(const float* __restrict__ H, const float* __restrict__ W,
                       const float* __restrict__ b, float* __restrict__ C,
                       int nrows, int K) {
    int j = threadIdx.x;
    int r0 = blockIdx.x * 16;
    float acc[16];
#pragma unroll
    for (int i = 0; i < 16; ++i) acc[i] = 0.0f;
    int K4 = K >> 2;
    const float4* H4 = (const float4*)H;
    for (int k4 = 0; k4 < K4; ++k4) {
        float w0 = W[(size_t)(k4 * 4 + 0) * 256 + j];
        float w1 = W[(size_t)(k4 * 4 + 1) * 256 + j];
        float w2 = W[(size_t)(k4 * 4 + 2) * 256 + j];
        float w3 = W[(size_t)(k4 * 4 + 3) * 256 + j];
#pragma unroll
        for (int i = 0; i < 16; ++i) {
            float4 h = H4[(size_t)(r0 + i) * K4 + k4];
            acc[i] = fmaf(h.x, w0, acc[i]);
            acc[i] = fmaf(h.y, w1, acc[i]);
            acc[i] = fmaf(h.z, w2, acc[i]);
            acc[i] = fmaf(h.w, w3, acc[i]);
        }
    }
    float bj = b[j];
#pragma unroll
    for (int i = 0; i < 16; ++i) {
        int r = r0 + i;
        if (r < nrows) C[(size_t)r * 256 + j] = acc[i] + bj;
    }
}

#define LRELU(v) ((v) >= 0.0f ? (v) : 0.2f * (v))

// K7: per-dst-node alpha scores.  One wave (64 lanes) per node; lane covers
// hc = 4*lane..4*lane+3 (all within head h = lane>>4).  xr[dst] stays in regs.
__global__ void k_alpha(const float* __restrict__ XL, const float* __restrict__ XR,
                        const float* __restrict__ we, const float* __restrict__ att,
                        const int* __restrict__ csr_src, const float* __restrict__ csr_ea,
                        const int* __restrict__ off, float* __restrict__ alpha, int n) {
    int wid = (blockIdx.x * 256 + threadIdx.x) >> 6;
    int lane = threadIdx.x & 63;
    if (wid >= n) return;
    const float4* XL4 = (const float4*)XL;
    float4 xr = ((const float4*)XR)[(size_t)wid * 64 + lane];
    float4 wv = ((const float4*)we)[lane];
    float4 av = ((const float4*)att)[lane];
    int p0 = off[wid], p1 = off[wid + 1];
    for (int p = p0; p < p1; ++p) {
        int s = csr_src[p];
        float eav = csr_ea[p];
        float4 xl = XL4[(size_t)s * 64 + lane];
        float t0 = xl.x + xr.x + eav * wv.x; t0 = LRELU(t0);
        float t1 = xl.y + xr.y + eav * wv.y; t1 = LRELU(t1);
        float t2 = xl.z + xr.z + eav * wv.z; t2 = LRELU(t2);
        float t3 = xl.w + xr.w + eav * wv.w; t3 = LRELU(t3);
        float sum = t0 * av.x + t1 * av.y + t2 * av.z + t3 * av.w;
        sum += __shfl_xor(sum, 1, 16);
        sum += __shfl_xor(sum, 2, 16);
        sum += __shfl_xor(sum, 4, 16);
        sum += __shfl_xor(sum, 8, 16);
        if ((lane & 15) == 0) alpha[(size_t)p * 4 + (lane >> 4)] = sum;
    }
}

// K8: per-dst-node softmax + weighted aggregation + bias + relu.
// Phase A: lane-parallel max/sum over the segment (lane -> edge p0+(lane>>2),
// head lane&3; stride 16 edges).  Phase B: loop edges, acc += a * xl[src].
__global__ void k_agg(const float* __restrict__ XL, const float* __restrict__ alpha,
                      const int* __restrict__ off, const int* __restrict__ csr_src,
                      const float* __restrict__ bias, float* __restrict__ out, int n) {
    int wid = (blockIdx.x * 256 + threadIdx.x) >> 6;
    int lane = threadIdx.x & 63;
    if (wid >= n) return;
    int p0 = off[wid], p1 = off[wid + 1];
    int h4 = lane & 3;
    float m = -3.0e38f;
    for (int p = p0 + (lane >> 2); p < p1; p += 16)
        m = fmaxf(m, alpha[(size_t)p * 4 + h4]);
    m = fmaxf(m, __shfl_xor(m, 4));
    m = fmaxf(m, __shfl_xor(m, 8));
    m = fmaxf(m, __shfl_xor(m, 16));
    m = fmaxf(m, __shfl_xor(m, 32));
    float s = 0.0f;
    for (int p = p0 + (lane >> 2); p < p1; p += 16)
        s += __expf(alpha[(size_t)p * 4 + h4] - m);
    s += __shfl_xor(s, 4);
    s += __shfl_xor(s, 8);
    s += __shfl_xor(s, 16);
    s += __shfl_xor(s, 32);
    int myh = lane >> 4;                 // head for this lane's hc block
    float mh = __shfl(m, myh);           // lane k (k<4) holds class k result
    float sh = __shfl(s, myh);
    float inv = 1.0f / sh;
    const float4* XL4 = (const float4*)XL;
    float ax = 0.f, ay = 0.f, az = 0.f, aw = 0.f;
    for (int p = p0; p < p1; ++p) {
        float a = __expf(alpha[(size_t)p * 4 + myh] - mh) * inv;
        int src = csr_src[p];
        float4 xl = XL4[(size_t)src * 64 + lane];
        ax = fmaf(a, xl.x, ax);
        ay = fmaf(a, xl.y, ay);
        az = fmaf(a, xl.z, az);
        aw = fmaf(a, xl.w, aw);
    }
    float4 bv = ((const float4*)bias)[lane];
    float4 o;
    o.x = fmaxf(ax + bv.x, 0.f);
    o.y = fmaxf(ay + bv.y, 0.f);
    o.z = fmaxf(az + bv.z, 0.f);
    o.w = fmaxf(aw + bv.w, 0.f);
    ((float4*)out)[(size_t)wid * 64 + lane] = o;
}

// K9: global mean pool.  batch is sorted; block handles 512 consecutive nodes,
// 256 threads = feature columns, running accumulator flushed on graph change.
__global__ void k_pool(const float* __restrict__ h, const int* __restrict__ batch,
                       float* __restrict__ gsum, float* __restrict__ gcnt, int n) {
    int j = threadIdx.x;
    int start = blockIdx.x * 512;
    if (start >= n) return;
    int end = start + 512; if (end > n) end = n;
    int cur = batch[start];
    float acc = 0.0f, cnt = 0.0f;
    for (int i = start; i < end; ++i) {
        int g = batch[i];
        if (g != cur) {
            atomicAdd(&gsum[cur * 256 + j], acc);
            if (j == 0) atomicAdd(&gcnt[cur], cnt);
            acc = 0.0f; cnt = 0.0f; cur = g;
        }
        acc += h[(size_t)i * 256 + j];
        cnt += 1.0f;
    }
    atomicAdd(&gsum[cur * 256 + j], acc);
    if (j == 0) atomicAdd(&gcnt[cur], cnt);
}

// K10: post MLP: 256->128, LayerNorm, relu, 128->64, relu.  1 block per graph.
__global__ void k_mlp(const float* __restrict__ gsum, const float* __restrict__ gcnt,
                      const float* __restrict__ p1w, const float* __restrict__ p1b,
                      const float* __restrict__ lng, const float* __restrict__ lnb,
                      const float* __restrict__ p2w, const float* __restrict__ p2b,
                      float* __restrict__ out) {
    int g = blockIdx.x;
    int t = threadIdx.x; // 128
    __shared__ float gv[256];
    __shared__ float z[128];
    __shared__ float red[128];
    float invc = 1.0f / fmaxf(gcnt[g], 1.0f);
    gv[t]       = gsum[g * 256 + t] * invc;
    gv[t + 128] = gsum[g * 256 + 128 + t] * invc;
    __syncthreads();
    float z1 = p1b[t];
    for (int k = 0; k < 256; ++k) z1 = fmaf(gv[k], p1w[k * 128 + t], z1);
    red[t] = z1;
    __syncthreads();
    for (int d = 64; d > 0; d >>= 1) { if (t < d) red[t] += red[t + d]; __syncthreads(); }
    float mu = red[0] * (1.0f / 128.0f);
    __syncthreads();
    float dz = z1 - mu;
    red[t] = dz * dz;
    __syncthreads();
    for (int d = 64; d > 0; d >>= 1) { if (t < d) red[t] += red[t + d]; __syncthreads(); }
    float var = red[0] * (1.0f / 128.0f);
    float zn = dz * rsqrtf(var + 1e-5f) * lng[t] + lnb[t];
    z[t] = fmaxf(zn, 0.0f);
    __syncthreads();
    if (t < 64) {
        float o = p2b[t];
        for (int k = 0; k < 128; ++k) o = fmaf(z[k], p2w[k * 64 + t], o);
        out[g * 64 + t] = fmaxf(o, 0.0f);
    }
}

extern "C" void kernel_launch(void* const* d_in, const int* in_sizes, int n_in,
                              void* d_out, int out_size, void* d_ws, size_t ws_size,
                              hipStream_t stream) {
    const float* x      = (const float*)d_in[0];
    const int*   ei     = (const int*)d_in[1];
    const float* ea     = (const float*)d_in[2];
    const int*   batch  = (const int*)d_in[3];
    const float* enc_w  = (const float*)d_in[4];
    const float* enc_b  = (const float*)d_in[5];
    const float* g1_wl  = (const float*)d_in[6];
    const float* g1_bl  = (const float*)d_in[7];
    const float* g1_wr  = (const float*)d_in[8];
    const float* g1_br  = (const float*)d_in[9];
    const float* g1_we  = (const float*)d_in[10];
    const float* g1_att = (const float*)d_in[11];
    const float* g1_bias= (const float*)d_in[12];
    const float* g2_wl  = (const float*)d_in[13];
    const float* g2_bl  = (const float*)d_in[14];
    const float* g2_wr  = (const float*)d_in[15];
    const float* g2_br  = (const float*)d_in[16];
    const float* g2_we  = (const float*)d_in[17];
    const float* g2_att = (const float*)d_in[18];
    const float* g2_bias= (const float*)d_in[19];
    const float* p1_w   = (const float*)d_in[20];
    const float* p1_b   = (const float*)d_in[21];
    const float* ln_g   = (const float*)d_in[22];
    const float* ln_b   = (const float*)d_in[23];
    const float* p2_w   = (const float*)d_in[24];
    const float* p2_b   = (const float*)d_in[25];
    float* out = (float*)d_out;

    const int N  = in_sizes[3];
    const int E  = in_sizes[1] / 2;
    const int EE = E + N;

    // workspace carve (floats)
    float* ws    = (float*)d_ws;
    float* A     = ws;                         // xl  [N,256]
    float* B     = A + (size_t)N * 256;        // xr  [N,256]
    float* C     = B + (size_t)N * 256;        // layer out / h  [N,256]
    float* h0    = C + (size_t)N * 256;        // encoder out [N,64]
    float* alpha = h0 + (size_t)N * 64;        // [EE,4]
    float* csr_ea= alpha + (size_t)EE * 4;     // [EE]
    float* deg   = csr_ea + EE;                // [N]   -- zeroed region start
    float* lsum  = deg + N;                    // [N]
    float* gsum  = lsum + N;                   // [32*256]
    float* gcnt  = gsum + 32 * 256;            // [32]
    int*   cursor= (int*)(gcnt + 32);          // [N]   -- zeroed region end
    int*   off   = cursor + N;                 // [N+1]
    int*   csr_src = off + (N + 1);            // [EE]

    hipMemsetAsync(deg, 0, (size_t)(3 * N + 32 * 256 + 32) * sizeof(float), stream);

    k_deg<<<CDIV(E, 256), 256, 0, stream>>>(ei, ea, deg, lsum, E);
    k_loopattr<<<CDIV(N, 256), 256, 0, stream>>>(lsum, deg, N);
    k_scan<<<1, 1024, 0, stream>>>(deg, off, N);
    k_fill<<<CDIV(EE, 256), 256, 0, stream>>>(ei, ea, lsum, off, cursor, csr_src, csr_ea, E, N);
    k_enc<<<CDIV(N * 64, 256), 256, 0, stream>>>(x, enc_w, enc_b, h0, N);

    // ---- GAT layer 1 (in dim 64) ----
    k_gemm<<<CDIV(N, 16), 256, 0, stream>>>(h0, g1_wl, g1_bl, A, N, 64);
    k_gemm<<<CDIV(N, 16), 256, 0, stream>>>(h0, g1_wr, g1_br, B, N, 64);
    k_alpha<<<CDIV(N, 4), 256, 0, stream>>>(A, B, g1_we, g1_att, csr_src, csr_ea, off, alpha, N);
    k_agg<<<CDIV(N, 4), 256, 0, stream>>>(A, alpha, off, csr_src, g1_bias, C, N);

    // ---- GAT layer 2 (in dim 256) ----
    k_gemm<<<CDIV(N, 16), 256, 0, stream>>>(C, g2_wl, g2_bl, A, N, 256);
    k_gemm<<<CDIV(N, 16), 256, 0, stream>>>(C, g2_wr, g2_br, B, N, 256);
    k_alpha<<<CDIV(N, 4), 256, 0, stream>>>(A, B, g2_we, g2_att, csr_src, csr_ea, off, alpha, N);
    k_agg<<<CDIV(N, 4), 256, 0, stream>>>(A, alpha, off, csr_src, g2_bias, C, N);

    // ---- pool + MLP ----
    k_pool<<<CDIV(N, 512), 256, 0, stream>>>(C, batch, gsum, gcnt, N);
    k_mlp<<<32, 128, 0, stream>>>(gsum, gcnt, p1_w, p1_b, ln_g, ln_b, p2_w, p2_b, out);
}

// Round 2
// 1141.177 us; speedup vs baseline: 1.3024x; 1.3024x over previous
//
#include <hip/hip_runtime.h>

#define CDIV(a,b) (((a)+(b)-1)/(b))

typedef __bf16 bf16_t;
typedef bf16_t bf16x8 __attribute__((ext_vector_type(8)));
typedef bf16_t bf16x4 __attribute__((ext_vector_type(4)));
typedef float floatx4 __attribute__((ext_vector_type(4)));

// ---------------------------------------------------------------------------
// K1: per-original-edge degree count + edge_attr sum (for self-loop fill)
__global__ void k_deg(const int* __restrict__ ei, const float* __restrict__ ea,
                      float* __restrict__ deg, float* __restrict__ lsum, int E) {
    int e = blockIdx.x * 256 + threadIdx.x;
    if (e >= E) return;
    int d = ei[E + e];
    atomicAdd(&deg[d], 1.0f);
    atomicAdd(&lsum[d], ea[e]);
}

// K2: loop_attr[n] = lsum[n] / max(deg[n], 1)   (in place on lsum)
__global__ void k_loopattr(float* __restrict__ lsum, const float* __restrict__ deg, int n) {
    int i = blockIdx.x * 256 + threadIdx.x;
    if (i >= n) return;
    lsum[i] = lsum[i] / fmaxf(deg[i], 1.0f);
}

// K3: exclusive scan of (deg[n]+1) -> off[0..n], single block of 1024 threads
__global__ void k_scan(const float* __restrict__ deg, int* __restrict__ off, int n) {
    __shared__ int part[1024];
    int t = threadIdx.x;
    int chunk = (n + 1023) / 1024;
    int s0 = t * chunk;
    int s1 = s0 + chunk; if (s1 > n) s1 = n; if (s0 > n) s0 = n;
    int s = 0;
    for (int i = s0; i < s1; ++i) s += (int)deg[i] + 1;
    part[t] = s;
    __syncthreads();
    for (int d = 1; d < 1024; d <<= 1) {
        int v = (t >= d) ? part[t - d] : 0;
        __syncthreads();
        part[t] += v;
        __syncthreads();
    }
    int excl = (t == 0) ? 0 : part[t - 1];
    for (int i = s0; i < s1; ++i) { off[i] = excl; excl += (int)deg[i] + 1; }
    if (t == 1023) off[n] = excl;
}

// K4: CSR fill over extended edges (E originals + n self loops)
__global__ void k_fill(const int* __restrict__ ei, const float* __restrict__ ea,
                       const float* __restrict__ lattr, const int* __restrict__ off,
                       int* __restrict__ cursor, int* __restrict__ csr_src,
                       float* __restrict__ csr_ea, int E, int n) {
    int e = blockIdx.x * 256 + threadIdx.x;
    int EE = E + n;
    if (e >= EE) return;
    int s, d; float a;
    if (e < E) { s = ei[e]; d = ei[E + e]; a = ea[e]; }
    else       { s = e - E; d = s;         a = lattr[s]; }
    int pos = off[d] + atomicAdd(&cursor[d], 1);
    csr_src[pos] = s;
    csr_ea[pos] = a;
}

// K5: encoder  h0b[n,64] = bf16(relu(x[n,:4] @ enc_w + enc_b))
// (h0 is only consumed by the layer-1 MFMA GEMMs -> emit bf16 directly)
__global__ void k_enc(const float* __restrict__ x, const float* __restrict__ w,
                      const float* __restrict__ b, bf16_t* __restrict__ h0, int n) {
    int idx = blockIdx.x * 256 + threadIdx.x;
    if (idx >= n * 64) return;
    int nn = idx >> 6, j = idx & 63;
    const float* xr = x + (size_t)nn * 4;
    float s = b[j];
#pragma unroll
    for (int k = 0; k < 4; ++k) s = fmaf(xr[k], w[k * 64 + j], s);
    h0[idx] = (bf16_t)fmaxf(s, 0.0f);
}

// K5b: fp32 -> bf16 cast, 4 elems/thread (n must be multiple of 4)
__global__ void k_cast4(const float* __restrict__ in, bf16_t* __restrict__ out, int n4) {
    int i = blockIdx.x * 256 + threadIdx.x;
    if (i >= n4) return;
    float4 v = ((const float4*)in)[i];
    bf16x4 o;
    o.x = (bf16_t)v.x; o.y = (bf16_t)v.y; o.z = (bf16_t)v.z; o.w = (bf16_t)v.w;
    *(bf16x4*)&out[(size_t)i * 4] = o;
}

// K5c: weight transpose+cast  W[K,256] fp32 -> Wt[256,K] bf16
__global__ void k_wcast(const float* __restrict__ W, bf16_t* __restrict__ Wt, int K) {
    int idx = blockIdx.x * 256 + threadIdx.x;
    if (idx >= K * 256) return;
    int k = idx >> 8, n = idx & 255;
    Wt[(size_t)n * K + k] = (bf16_t)W[idx];
}

// K6: MFMA bf16 GEMM:  out[r, n0:n0+128] = Hb[r,:K] @ Wt[n,:K]^T + bias
// 128x128 tile, BK=32, 4 waves (each 32 rows x 128 cols), 16x16x32 mfma.
// LDS rows padded to 40 bf16 (80B) -> 2-way bank aliasing only (free).
__global__ __launch_bounds__(256) void k_gemm_mfma(
        const bf16_t* __restrict__ Hb, const bf16_t* __restrict__ Wt,
        const float* __restrict__ bias, float* __restrict__ out,
        int nrows, int K) {
    __shared__ bf16_t As[128 * 40];
    __shared__ bf16_t Bs[128 * 40];
    int tid = threadIdx.x;
    int w = tid >> 6, lane = tid & 63;
    int quad = lane >> 4, m = lane & 15;
    int row0 = blockIdx.x * 128;
    int n0 = blockIdx.y * 128;
    floatx4 acc[2][8];
#pragma unroll
    for (int rt = 0; rt < 2; ++rt)
#pragma unroll
        for (int ct = 0; ct < 8; ++ct)
            acc[rt][ct] = (floatx4){0.f, 0.f, 0.f, 0.f};

    for (int k0 = 0; k0 < K; k0 += 32) {
        __syncthreads();
#pragma unroll
        for (int i = 0; i < 2; ++i) {          // stage A: 128 rows x 32 k
            int c = tid + i * 256;
            int r = c >> 2, kc = c & 3;
            int gr = row0 + r; if (gr >= nrows) gr = nrows - 1;
            bf16x8 v = *(const bf16x8*)&Hb[(size_t)gr * K + k0 + kc * 8];
            *(bf16x8*)&As[r * 40 + kc * 8] = v;
        }
#pragma unroll
        for (int i = 0; i < 2; ++i) {          // stage B: 128 cols x 32 k
            int c = tid + i * 256;
            int r = c >> 2, kc = c & 3;
            bf16x8 v = *(const bf16x8*)&Wt[(size_t)(n0 + r) * K + k0 + kc * 8];
            *(bf16x8*)&Bs[r * 40 + kc * 8] = v;
        }
        __syncthreads();
        bf16x8 af[2], bfr[8];
        af[0] = *(bf16x8*)&As[(w * 32 + m) * 40 + quad * 8];
        af[1] = *(bf16x8*)&As[(w * 32 + 16 + m) * 40 + quad * 8];
#pragma unroll
        for (int ct = 0; ct < 8; ++ct)
            bfr[ct] = *(bf16x8*)&Bs[(ct * 16 + m) * 40 + quad * 8];
#pragma unroll
        for (int ct = 0; ct < 8; ++ct) {
            acc[0][ct] = __builtin_amdgcn_mfma_f32_16x16x32_bf16(af[0], bfr[ct], acc[0][ct], 0, 0, 0);
            acc[1][ct] = __builtin_amdgcn_mfma_f32_16x16x32_bf16(af[1], bfr[ct], acc[1][ct], 0, 0, 0);
        }
    }
#pragma unroll
    for (int ct = 0; ct < 8; ++ct) {
        int col = n0 + ct * 16 + m;
        float bv = bias[col];
#pragma unroll
        for (int rt = 0; rt < 2; ++rt) {
#pragma unroll
            for (int i = 0; i < 4; ++i) {
                int row = row0 + w * 32 + rt * 16 + quad * 4 + i;
                if (row < nrows) out[(size_t)row * 256 + col] = acc[rt][ct][i] + bv;
            }
        }
    }
}

#define LRELU(v) ((v) >= 0.0f ? (v) : 0.2f * (v))

// K7: per-dst-node alpha scores.  One wave (64 lanes) per node; lane covers
// hc = 4*lane..4*lane+3 (all within head h = lane>>4).  xr[dst] stays in regs.
__global__ void k_alpha(const float* __restrict__ XL, const float* __restrict__ XR,
                        const float* __restrict__ we, const float* __restrict__ att,
                        const int* __restrict__ csr_src, const float* __restrict__ csr_ea,
                        const int* __restrict__ off, float* __restrict__ alpha, int n) {
    int wid = (blockIdx.x * 256 + threadIdx.x) >> 6;
    int lane = threadIdx.x & 63;
    if (wid >= n) return;
    const float4* XL4 = (const float4*)XL;
    float4 xr = ((const float4*)XR)[(size_t)wid * 64 + lane];
    float4 wv = ((const float4*)we)[lane];
    float4 av = ((const float4*)att)[lane];
    int p0 = off[wid], p1 = off[wid + 1];
    for (int p = p0; p < p1; ++p) {
        int s = csr_src[p];
        float eav = csr_ea[p];
        float4 xl = XL4[(size_t)s * 64 + lane];
        float t0 = xl.x + xr.x + eav * wv.x; t0 = LRELU(t0);
        float t1 = xl.y + xr.y + eav * wv.y; t1 = LRELU(t1);
        float t2 = xl.z + xr.z + eav * wv.z; t2 = LRELU(t2);
        float t3 = xl.w + xr.w + eav * wv.w; t3 = LRELU(t3);
        float sum = t0 * av.x + t1 * av.y + t2 * av.z + t3 * av.w;
        sum += __shfl_xor(sum, 1, 16);
        sum += __shfl_xor(sum, 2, 16);
        sum += __shfl_xor(sum, 4, 16);
        sum += __shfl_xor(sum, 8, 16);
        if ((lane & 15) == 0) alpha[(size_t)p * 4 + (lane >> 4)] = sum;
    }
}

// K8: per-dst-node softmax + weighted aggregation + bias + relu.
__global__ void k_agg(const float* __restrict__ XL, const float* __restrict__ alpha,
                      const int* __restrict__ off, const int* __restrict__ csr_src,
                      const float* __restrict__ bias, float* __restrict__ out, int n) {
    int wid = (blockIdx.x * 256 + threadIdx.x) >> 6;
    int lane = threadIdx.x & 63;
    if (wid >= n) return;
    int p0 = off[wid], p1 = off[wid + 1];
    int h4 = lane & 3;
    float m = -3.0e38f;
    for (int p = p0 + (lane >> 2); p < p1; p += 16)
        m = fmaxf(m, alpha[(size_t)p * 4 + h4]);
    m = fmaxf(m, __shfl_xor(m, 4));
    m = fmaxf(m, __shfl_xor(m, 8));
    m = fmaxf(m, __shfl_xor(m, 16));
    m = fmaxf(m, __shfl_xor(m, 32));
    float s = 0.0f;
    for (int p = p0 + (lane >> 2); p < p1; p += 16)
        s += __expf(alpha[(size_t)p * 4 + h4] - m);
    s += __shfl_xor(s, 4);
    s += __shfl_xor(s, 8);
    s += __shfl_xor(s, 16);
    s += __shfl_xor(s, 32);
    int myh = lane >> 4;
    float mh = __shfl(m, myh);
    float sh = __shfl(s, myh);
    float inv = 1.0f / sh;
    const float4* XL4 = (const float4*)XL;
    float ax = 0.f, ay = 0.f, az = 0.f, aw = 0.f;
    for (int p = p0; p < p1; ++p) {
        float a = __expf(alpha[(size_t)p * 4 + myh] - mh) * inv;
        int src = csr_src[p];
        float4 xl = XL4[(size_t)src * 64 + lane];
        ax = fmaf(a, xl.x, ax);
        ay = fmaf(a, xl.y, ay);
        az = fmaf(a, xl.z, az);
        aw = fmaf(a, xl.w, aw);
    }
    float4 bv = ((const float4*)bias)[lane];
    float4 o;
    o.x = fmaxf(ax + bv.x, 0.f);
    o.y = fmaxf(ay + bv.y, 0.f);
    o.z = fmaxf(az + bv.z, 0.f);
    o.w = fmaxf(aw + bv.w, 0.f);
    ((float4*)out)[(size_t)wid * 64 + lane] = o;
}

// K9: global mean pool.  batch sorted; running accumulator, flush on change.
__global__ void k_pool(const float* __restrict__ h, const int* __restrict__ batch,
                       float* __restrict__ gsum, float* __restrict__ gcnt, int n) {
    int j = threadIdx.x;
    int start = blockIdx.x * 512;
    if (start >= n) return;
    int end = start + 512; if (end > n) end = n;
    int cur = batch[start];
    float acc = 0.0f, cnt = 0.0f;
    for (int i = start; i < end; ++i) {
        int g = batch[i];
        if (g != cur) {
            atomicAdd(&gsum[cur * 256 + j], acc);
            if (j == 0) atomicAdd(&gcnt[cur], cnt);
            acc = 0.0f; cnt = 0.0f; cur = g;
        }
        acc += h[(size_t)i * 256 + j];
        cnt += 1.0f;
    }
    atomicAdd(&gsum[cur * 256 + j], acc);
    if (j == 0) atomicAdd(&gcnt[cur], cnt);
}

// K10: post MLP: 256->128, LayerNorm, relu, 128->64, relu.  1 block per graph.
__global__ void k_mlp(const float* __restrict__ gsum, const float* __restrict__ gcnt,
                      const float* __restrict__ p1w, const float* __restrict__ p1b,
                      const float* __restrict__ lng, const float* __restrict__ lnb,
                      const float* __restrict__ p2w, const float* __restrict__ p2b,
                      float* __restrict__ out) {
    int g = blockIdx.x;
    int t = threadIdx.x; // 128
    __shared__ float gv[256];
    __shared__ float z[128];
    __shared__ float red[128];
    float invc = 1.0f / fmaxf(gcnt[g], 1.0f);
    gv[t]       = gsum[g * 256 + t] * invc;
    gv[t + 128] = gsum[g * 256 + 128 + t] * invc;
    __syncthreads();
    float z1 = p1b[t];
    for (int k = 0; k < 256; ++k) z1 = fmaf(gv[k], p1w[k * 128 + t], z1);
    red[t] = z1;
    __syncthreads();
    for (int d = 64; d > 0; d >>= 1) { if (t < d) red[t] += red[t + d]; __syncthreads(); }
    float mu = red[0] * (1.0f / 128.0f);
    __syncthreads();
    float dz = z1 - mu;
    red[t] = dz * dz;
    __syncthreads();
    for (int d = 64; d > 0; d >>= 1) { if (t < d) red[t] += red[t + d]; __syncthreads(); }
    float var = red[0] * (1.0f / 128.0f);
    float zn = dz * rsqrtf(var + 1e-5f) * lng[t] + lnb[t];
    z[t] = fmaxf(zn, 0.0f);
    __syncthreads();
    if (t < 64) {
        float o = p2b[t];
        for (int k = 0; k < 128; ++k) o = fmaf(z[k], p2w[k * 64 + t], o);
        out[g * 64 + t] = fmaxf(o, 0.0f);
    }
}

extern "C" void kernel_launch(void* const* d_in, const int* in_sizes, int n_in,
                              void* d_out, int out_size, void* d_ws, size_t ws_size,
                              hipStream_t stream) {
    const float* x      = (const float*)d_in[0];
    const int*   ei     = (const int*)d_in[1];
    const float* ea     = (const float*)d_in[2];
    const int*   batch  = (const int*)d_in[3];
    const float* enc_w  = (const float*)d_in[4];
    const float* enc_b  = (const float*)d_in[5];
    const float* g1_wl  = (const float*)d_in[6];
    const float* g1_bl  = (const float*)d_in[7];
    const float* g1_wr  = (const float*)d_in[8];
    const float* g1_br  = (const float*)d_in[9];
    const float* g1_we  = (const float*)d_in[10];
    const float* g1_att = (const float*)d_in[11];
    const float* g1_bias= (const float*)d_in[12];
    const float* g2_wl  = (const float*)d_in[13];
    const float* g2_bl  = (const float*)d_in[14];
    const float* g2_wr  = (const float*)d_in[15];
    const float* g2_br  = (const float*)d_in[16];
    const float* g2_we  = (const float*)d_in[17];
    const float* g2_att = (const float*)d_in[18];
    const float* g2_bias= (const float*)d_in[19];
    const float* p1_w   = (const float*)d_in[20];
    const float* p1_b   = (const float*)d_in[21];
    const float* ln_g   = (const float*)d_in[22];
    const float* ln_b   = (const float*)d_in[23];
    const float* p2_w   = (const float*)d_in[24];
    const float* p2_b   = (const float*)d_in[25];
    float* out = (float*)d_out;

    const int N  = in_sizes[3];
    const int E  = in_sizes[1] / 2;
    const int EE = E + N;

    // workspace carve (bf16 buffers first for 16B alignment)
    bf16_t* Hb  = (bf16_t*)d_ws;               // [N,256] bf16 (layer1 uses [N,64])
    bf16_t* Wtl = Hb + (size_t)N * 256;        // [256,256] bf16
    bf16_t* Wtr = Wtl + 256 * 256;             // [256,256] bf16
    float* A     = (float*)(Wtr + 256 * 256);  // xl  [N,256]
    float* B     = A + (size_t)N * 256;        // xr  [N,256]
    float* C     = B + (size_t)N * 256;        // layer out / h  [N,256]
    float* alpha = C + (size_t)N * 256;        // [EE,4]
    float* csr_ea= alpha + (size_t)EE * 4;     // [EE]
    float* deg   = csr_ea + EE;                // [N]   -- zeroed region start
    float* lsum  = deg + N;                    // [N]
    float* gsum  = lsum + N;                   // [32*256]
    float* gcnt  = gsum + 32 * 256;            // [32]
    int*   cursor= (int*)(gcnt + 32);          // [N]   -- zeroed region end
    int*   off   = cursor + N;                 // [N+1]
    int*   csr_src = off + (N + 1);            // [EE]

    hipMemsetAsync(deg, 0, (size_t)(3 * N + 32 * 256 + 32) * sizeof(float), stream);

    k_deg<<<CDIV(E, 256), 256, 0, stream>>>(ei, ea, deg, lsum, E);
    k_loopattr<<<CDIV(N, 256), 256, 0, stream>>>(lsum, deg, N);
    k_scan<<<1, 1024, 0, stream>>>(deg, off, N);
    k_fill<<<CDIV(EE, 256), 256, 0, stream>>>(ei, ea, lsum, off, cursor, csr_src, csr_ea, E, N);
    k_enc<<<CDIV(N * 64, 256), 256, 0, stream>>>(x, enc_w, enc_b, Hb, N);

    dim3 ggrid(CDIV(N, 128), 2);

    // ---- GAT layer 1 (in dim 64) ----
    k_wcast<<<CDIV(64 * 256, 256), 256, 0, stream>>>(g1_wl, Wtl, 64);
    k_wcast<<<CDIV(64 * 256, 256), 256, 0, stream>>>(g1_wr, Wtr, 64);
    k_gemm_mfma<<<ggrid, 256, 0, stream>>>(Hb, Wtl, g1_bl, A, N, 64);
    k_gemm_mfma<<<ggrid, 256, 0, stream>>>(Hb, Wtr, g1_br, B, N, 64);
    k_alpha<<<CDIV(N, 4), 256, 0, stream>>>(A, B, g1_we, g1_att, csr_src, csr_ea, off, alpha, N);
    k_agg<<<CDIV(N, 4), 256, 0, stream>>>(A, alpha, off, csr_src, g1_bias, C, N);

    // ---- GAT layer 2 (in dim 256) ----
    k_cast4<<<CDIV(N * 64, 256), 256, 0, stream>>>(C, Hb, N * 64);  // N*256/4 elems
    k_wcast<<<CDIV(256 * 256, 256), 256, 0, stream>>>(g2_wl, Wtl, 256);
    k_wcast<<<CDIV(256 * 256, 256), 256, 0, stream>>>(g2_wr, Wtr, 256);
    k_gemm_mfma<<<ggrid, 256, 0, stream>>>(Hb, Wtl, g2_bl, A, N, 256);
    k_gemm_mfma<<<ggrid, 256, 0, stream>>>(Hb, Wtr, g2_br, B, N, 256);
    k_alpha<<<CDIV(N, 4), 256, 0, stream>>>(A, B, g2_we, g2_att, csr_src, csr_ea, off, alpha, N);
    k_agg<<<CDIV(N, 4), 256, 0, stream>>>(A, alpha, off, csr_src, g2_bias, C, N);

    // ---- pool + MLP ----
    k_pool<<<CDIV(N, 512), 256, 0, stream>>>(C, batch, gsum, gcnt, N);
    k_mlp<<<32, 128, 0, stream>>>(gsum, gcnt, p1_w, p1_b, ln_g, ln_b, p2_w, p2_b, out);
}

// Round 3
// 709.215 us; speedup vs baseline: 2.0957x; 1.6091x over previous
//
#include <hip/hip_runtime.h>

#define CDIV(a,b) (((a)+(b)-1)/(b))

typedef __bf16 bf16_t;
typedef bf16_t bf16x8 __attribute__((ext_vector_type(8)));
typedef bf16_t bf16x4 __attribute__((ext_vector_type(4)));
typedef float floatx4 __attribute__((ext_vector_type(4)));

// ---------------------------------------------------------------------------
// K1: per-original-edge degree count + edge_attr sum (for self-loop fill)
__global__ void k_deg(const int* __restrict__ ei, const float* __restrict__ ea,
                      float* __restrict__ deg, float* __restrict__ lsum, int E) {
    int e = blockIdx.x * 256 + threadIdx.x;
    if (e >= E) return;
    int d = ei[E + e];
    atomicAdd(&deg[d], 1.0f);
    atomicAdd(&lsum[d], ea[e]);
}

// K2: loop_attr[n] = lsum[n] / max(deg[n], 1)   (in place on lsum)
__global__ void k_loopattr(float* __restrict__ lsum, const float* __restrict__ deg, int n) {
    int i = blockIdx.x * 256 + threadIdx.x;
    if (i >= n) return;
    lsum[i] = lsum[i] / fmaxf(deg[i], 1.0f);
}

// K3: exclusive scan of (deg[n]+1) -> off[0..n], single block of 1024 threads
__global__ void k_scan(const float* __restrict__ deg, int* __restrict__ off, int n) {
    __shared__ int part[1024];
    int t = threadIdx.x;
    int chunk = (n + 1023) / 1024;
    int s0 = t * chunk;
    int s1 = s0 + chunk; if (s1 > n) s1 = n; if (s0 > n) s0 = n;
    int s = 0;
    for (int i = s0; i < s1; ++i) s += (int)deg[i] + 1;
    part[t] = s;
    __syncthreads();
    for (int d = 1; d < 1024; d <<= 1) {
        int v = (t >= d) ? part[t - d] : 0;
        __syncthreads();
        part[t] += v;
        __syncthreads();
    }
    int excl = (t == 0) ? 0 : part[t - 1];
    for (int i = s0; i < s1; ++i) { off[i] = excl; excl += (int)deg[i] + 1; }
    if (t == 1023) off[n] = excl;
}

// K4: CSR fill over extended edges (E originals + n self loops)
__global__ void k_fill(const int* __restrict__ ei, const float* __restrict__ ea,
                       const float* __restrict__ lattr, const int* __restrict__ off,
                       int* __restrict__ cursor, int* __restrict__ csr_src,
                       float* __restrict__ csr_ea, int E, int n) {
    int e = blockIdx.x * 256 + threadIdx.x;
    int EE = E + n;
    if (e >= EE) return;
    int s, d; float a;
    if (e < E) { s = ei[e]; d = ei[E + e]; a = ea[e]; }
    else       { s = e - E; d = s;         a = lattr[s]; }
    int pos = off[d] + atomicAdd(&cursor[d], 1);
    csr_src[pos] = s;
    csr_ea[pos] = a;
}

// K5: encoder  h0b[n,64] = bf16(relu(x[n,:4] @ enc_w + enc_b))
__global__ void k_enc(const float* __restrict__ x, const float* __restrict__ w,
                      const float* __restrict__ b, bf16_t* __restrict__ h0, int n) {
    int idx = blockIdx.x * 256 + threadIdx.x;
    if (idx >= n * 64) return;
    int nn = idx >> 6, j = idx & 63;
    const float* xr = x + (size_t)nn * 4;
    float s = b[j];
#pragma unroll
    for (int k = 0; k < 4; ++k) s = fmaf(xr[k], w[k * 64 + j], s);
    h0[idx] = (bf16_t)fmaxf(s, 0.0f);
}

// K5c: combined weight transpose+cast  Wl,Wr[K,256] fp32 -> Wt[512,K] bf16
// (row n of Wt = output col n; n<256 -> lin_l, n>=256 -> lin_r).  Also packs
// the combined bias vector.  kshift = log2(K).
__global__ void k_wcast2(const float* __restrict__ Wl, const float* __restrict__ Wr,
                         const float* __restrict__ bl, const float* __restrict__ br,
                         bf16_t* __restrict__ Wt, float* __restrict__ bias2,
                         int K, int kshift) {
    int idx = blockIdx.x * 256 + threadIdx.x;
    if (idx < 512) bias2[idx] = (idx < 256) ? bl[idx] : br[idx - 256];
    if (idx >= 512 * K) return;
    int nn = idx >> kshift, k = idx & (K - 1);
    float v = (nn < 256) ? Wl[k * 256 + nn] : Wr[k * 256 + (nn - 256)];
    Wt[idx] = (bf16_t)v;
}

// K6: MFMA bf16 GEMM:  [XL|XR][r, :] = Hb[r,:K] @ Wt^T + bias  (bf16 out)
// 128x128 tile, BK=32, 4 waves, 16x16x32 mfma.  LDS layout: 64B rows, 16B
// chunks XOR-swizzled by (q + (r>>1))&3 -> conflict-free b128 reads & writes.
__global__ __launch_bounds__(256) void k_gemm_mfma(
        const bf16_t* __restrict__ Hb, const bf16_t* __restrict__ Wt,
        const float* __restrict__ bias2, bf16_t* __restrict__ XL,
        bf16_t* __restrict__ XR, int nrows, int K) {
    __shared__ bf16_t As[128 * 32];
    __shared__ bf16_t Bs[128 * 32];
    int tid = threadIdx.x;
    int w = tid >> 6, lane = tid & 63;
    int quad = lane >> 4, m = lane & 15;
    int row0 = blockIdx.x * 128;
    int n0 = blockIdx.y * 128;
    floatx4 acc[2][8];
#pragma unroll
    for (int rt = 0; rt < 2; ++rt)
#pragma unroll
        for (int ct = 0; ct < 8; ++ct)
            acc[rt][ct] = (floatx4){0.f, 0.f, 0.f, 0.f};

    for (int k0 = 0; k0 < K; k0 += 32) {
        __syncthreads();
#pragma unroll
        for (int i = 0; i < 2; ++i) {          // stage A: 128 rows x 32 k
            int c = tid + i * 256;
            int r = c >> 2, kc = c & 3;
            int sw = (kc + (r >> 1)) & 3;
            int gr = row0 + r; if (gr >= nrows) gr = nrows - 1;
            bf16x8 v = *(const bf16x8*)&Hb[(size_t)gr * K + k0 + kc * 8];
            *(bf16x8*)&As[r * 32 + sw * 8] = v;
        }
#pragma unroll
        for (int i = 0; i < 2; ++i) {          // stage B: 128 cols x 32 k
            int c = tid + i * 256;
            int r = c >> 2, kc = c & 3;
            int sw = (kc + (r >> 1)) & 3;
            bf16x8 v = *(const bf16x8*)&Wt[(size_t)(n0 + r) * K + k0 + kc * 8];
            *(bf16x8*)&Bs[r * 32 + sw * 8] = v;
        }
        __syncthreads();
        bf16x8 af[2], bfr[8];
#pragma unroll
        for (int rt = 0; rt < 2; ++rt) {
            int ar = w * 32 + rt * 16 + m;
            af[rt] = *(bf16x8*)&As[ar * 32 + (((quad + (ar >> 1)) & 3) * 8)];
        }
#pragma unroll
        for (int ct = 0; ct < 8; ++ct) {
            int br = ct * 16 + m;
            bfr[ct] = *(bf16x8*)&Bs[br * 32 + (((quad + (br >> 1)) & 3) * 8)];
        }
#pragma unroll
        for (int ct = 0; ct < 8; ++ct) {
            acc[0][ct] = __builtin_amdgcn_mfma_f32_16x16x32_bf16(af[0], bfr[ct], acc[0][ct], 0, 0, 0);
            acc[1][ct] = __builtin_amdgcn_mfma_f32_16x16x32_bf16(af[1], bfr[ct], acc[1][ct], 0, 0, 0);
        }
    }
#pragma unroll
    for (int ct = 0; ct < 8; ++ct) {
        int col = n0 + ct * 16 + m;
        float bv = bias2[col];
        bf16_t* dst = (col < 256) ? XL : XR;
        int c2 = col & 255;
#pragma unroll
        for (int rt = 0; rt < 2; ++rt) {
#pragma unroll
            for (int i = 0; i < 4; ++i) {
                int row = row0 + w * 32 + rt * 16 + quad * 4 + i;
                if (row < nrows) dst[(size_t)row * 256 + c2] = (bf16_t)(acc[rt][ct][i] + bv);
            }
        }
    }
}

#define LRELU(v) ((v) >= 0.0f ? (v) : 0.2f * (v))

// K7: fused GATv2 conv — per-dst online softmax + aggregation in ONE pass
// over the CSR segment.  One wave per node; lane covers hc=4*lane..4*lane+3
// (head = lane>>4).  xl gathered once per edge (bf16, 512B/edge).
__global__ void k_conv(const bf16_t* __restrict__ XL, const bf16_t* __restrict__ XR,
                       const float* __restrict__ we, const float* __restrict__ att,
                       const int* __restrict__ csr_src, const float* __restrict__ csr_ea,
                       const int* __restrict__ off, const float* __restrict__ bias,
                       float* __restrict__ outf, bf16_t* __restrict__ outb, int n) {
    int wid = (blockIdx.x * 256 + threadIdx.x) >> 6;
    int lane = threadIdx.x & 63;
    if (wid >= n) return;
    bf16x4 xrb = *(const bf16x4*)&XR[(size_t)wid * 256 + lane * 4];
    float xr0 = (float)xrb.x, xr1 = (float)xrb.y, xr2 = (float)xrb.z, xr3 = (float)xrb.w;
    float4 wv = ((const float4*)we)[lane];
    float4 av = ((const float4*)att)[lane];
    int p0 = off[wid], p1 = off[wid + 1];
    float m = -3.0e38f, s = 0.0f;
    float a0 = 0.f, a1 = 0.f, a2 = 0.f, a3 = 0.f;
    for (int p = p0; p < p1; ++p) {
        int src = csr_src[p];
        float eav = csr_ea[p];
        bf16x4 xlb = *(const bf16x4*)&XL[(size_t)src * 256 + lane * 4];
        float x0 = (float)xlb.x, x1 = (float)xlb.y, x2 = (float)xlb.z, x3 = (float)xlb.w;
        float t0 = x0 + xr0 + eav * wv.x; t0 = LRELU(t0);
        float t1 = x1 + xr1 + eav * wv.y; t1 = LRELU(t1);
        float t2 = x2 + xr2 + eav * wv.z; t2 = LRELU(t2);
        float t3 = x3 + xr3 + eav * wv.w; t3 = LRELU(t3);
        float al = t0 * av.x + t1 * av.y + t2 * av.z + t3 * av.w;
        al += __shfl_xor(al, 1, 16);
        al += __shfl_xor(al, 2, 16);
        al += __shfl_xor(al, 4, 16);
        al += __shfl_xor(al, 8, 16);   // all 16 lanes of the head group hold alpha
        float mn = fmaxf(m, al);
        float sc = __expf(m - mn);     // first iter: exp(-inf) = 0
        float wg = __expf(al - mn);
        s = s * sc + wg;
        a0 = a0 * sc + wg * x0;
        a1 = a1 * sc + wg * x1;
        a2 = a2 * sc + wg * x2;
        a3 = a3 * sc + wg * x3;
        m = mn;
    }
    float inv = 1.0f / s;
    float4 bv = ((const float4*)bias)[lane];
    float o0 = fmaxf(a0 * inv + bv.x, 0.f);
    float o1 = fmaxf(a1 * inv + bv.y, 0.f);
    float o2 = fmaxf(a2 * inv + bv.z, 0.f);
    float o3 = fmaxf(a3 * inv + bv.w, 0.f);
    ((float4*)outf)[(size_t)wid * 64 + lane] = (float4){o0, o1, o2, o3};
    bf16x4 ob;
    ob.x = (bf16_t)o0; ob.y = (bf16_t)o1; ob.z = (bf16_t)o2; ob.w = (bf16_t)o3;
    *(bf16x4*)&outb[(size_t)wid * 256 + lane * 4] = ob;
}

// K9: global mean pool.  batch sorted; 64-node chunks -> ~800 blocks.
__global__ void k_pool(const float* __restrict__ h, const int* __restrict__ batch,
                       float* __restrict__ gsum, float* __restrict__ gcnt, int n) {
    int j = threadIdx.x;
    int start = blockIdx.x * 64;
    if (start >= n) return;
    int end = start + 64; if (end > n) end = n;
    int cur = batch[start];
    float acc = 0.0f, cnt = 0.0f;
    for (int i = start; i < end; ++i) {
        int g = batch[i];
        if (g != cur) {
            atomicAdd(&gsum[cur * 256 + j], acc);
            if (j == 0) atomicAdd(&gcnt[cur], cnt);
            acc = 0.0f; cnt = 0.0f; cur = g;
        }
        acc += h[(size_t)i * 256 + j];
        cnt += 1.0f;
    }
    atomicAdd(&gsum[cur * 256 + j], acc);
    if (j == 0) atomicAdd(&gcnt[cur], cnt);
}

// K10: post MLP: 256->128, LayerNorm, relu, 128->64, relu.  1 block per graph.
__global__ void k_mlp(const float* __restrict__ gsum, const float* __restrict__ gcnt,
                      const float* __restrict__ p1w, const float* __restrict__ p1b,
                      const float* __restrict__ lng, const float* __restrict__ lnb,
                      const float* __restrict__ p2w, const float* __restrict__ p2b,
                      float* __restrict__ out) {
    int g = blockIdx.x;
    int t = threadIdx.x; // 128
    __shared__ float gv[256];
    __shared__ float z[128];
    __shared__ float red[128];
    float invc = 1.0f / fmaxf(gcnt[g], 1.0f);
    gv[t]       = gsum[g * 256 + t] * invc;
    gv[t + 128] = gsum[g * 256 + 128 + t] * invc;
    __syncthreads();
    float z1 = p1b[t];
    for (int k = 0; k < 256; ++k) z1 = fmaf(gv[k], p1w[k * 128 + t], z1);
    red[t] = z1;
    __syncthreads();
    for (int d = 64; d > 0; d >>= 1) { if (t < d) red[t] += red[t + d]; __syncthreads(); }
    float mu = red[0] * (1.0f / 128.0f);
    __syncthreads();
    float dz = z1 - mu;
    red[t] = dz * dz;
    __syncthreads();
    for (int d = 64; d > 0; d >>= 1) { if (t < d) red[t] += red[t + d]; __syncthreads(); }
    float var = red[0] * (1.0f / 128.0f);
    float zn = dz * rsqrtf(var + 1e-5f) * lng[t] + lnb[t];
    z[t] = fmaxf(zn, 0.0f);
    __syncthreads();
    if (t < 64) {
        float o = p2b[t];
        for (int k = 0; k < 128; ++k) o = fmaf(z[k], p2w[k * 64 + t], o);
        out[g * 64 + t] = fmaxf(o, 0.0f);
    }
}

extern "C" void kernel_launch(void* const* d_in, const int* in_sizes, int n_in,
                              void* d_out, int out_size, void* d_ws, size_t ws_size,
                              hipStream_t stream) {
    const float* x      = (const float*)d_in[0];
    const int*   ei     = (const int*)d_in[1];
    const float* ea     = (const float*)d_in[2];
    const int*   batch  = (const int*)d_in[3];
    const float* enc_w  = (const float*)d_in[4];
    const float* enc_b  = (const float*)d_in[5];
    const float* g1_wl  = (const float*)d_in[6];
    const float* g1_bl  = (const float*)d_in[7];
    const float* g1_wr  = (const float*)d_in[8];
    const float* g1_br  = (const float*)d_in[9];
    const float* g1_we  = (const float*)d_in[10];
    const float* g1_att = (const float*)d_in[11];
    const float* g1_bias= (const float*)d_in[12];
    const float* g2_wl  = (const float*)d_in[13];
    const float* g2_bl  = (const float*)d_in[14];
    const float* g2_wr  = (const float*)d_in[15];
    const float* g2_br  = (const float*)d_in[16];
    const float* g2_we  = (const float*)d_in[17];
    const float* g2_att = (const float*)d_in[18];
    const float* g2_bias= (const float*)d_in[19];
    const float* p1_w   = (const float*)d_in[20];
    const float* p1_b   = (const float*)d_in[21];
    const float* ln_g   = (const float*)d_in[22];
    const float* ln_b   = (const float*)d_in[23];
    const float* p2_w   = (const float*)d_in[24];
    const float* p2_b   = (const float*)d_in[25];
    float* out = (float*)d_out;

    const int N  = in_sizes[3];
    const int E  = in_sizes[1] / 2;
    const int EE = E + N;

    // workspace carve (bf16 buffers first for 16B alignment)
    bf16_t* XL  = (bf16_t*)d_ws;               // [N,256] bf16
    bf16_t* XR  = XL + (size_t)N * 256;        // [N,256] bf16
    bf16_t* Hb  = XR + (size_t)N * 256;        // [N,256] bf16 (layer1 uses [N,64])
    bf16_t* Wt  = Hb + (size_t)N * 256;        // [512,256] bf16
    float* C     = (float*)(Wt + 512 * 256);   // layer-2 out (fp32, for pool) [N,256]
    float* csr_ea= C + (size_t)N * 256;        // [EE]
    float* bias2 = csr_ea + EE;                // [512]
    float* deg   = bias2 + 512;                // [N]   -- zeroed region start
    float* lsum  = deg + N;                    // [N]
    float* gsum  = lsum + N;                   // [32*256]
    float* gcnt  = gsum + 32 * 256;            // [32]
    int*   cursor= (int*)(gcnt + 32);          // [N]   -- zeroed region end
    int*   off   = cursor + N;                 // [N+1]
    int*   csr_src = off + (N + 1);            // [EE]

    hipMemsetAsync(deg, 0, (size_t)(3 * N + 32 * 256 + 32) * sizeof(float), stream);

    k_deg<<<CDIV(E, 256), 256, 0, stream>>>(ei, ea, deg, lsum, E);
    k_loopattr<<<CDIV(N, 256), 256, 0, stream>>>(lsum, deg, N);
    k_scan<<<1, 1024, 0, stream>>>(deg, off, N);
    k_fill<<<CDIV(EE, 256), 256, 0, stream>>>(ei, ea, lsum, off, cursor, csr_src, csr_ea, E, N);
    k_enc<<<CDIV(N * 64, 256), 256, 0, stream>>>(x, enc_w, enc_b, Hb, N);

    dim3 ggrid(CDIV(N, 128), 4);   // 4 col-tiles = 512 output cols (XL|XR)

    // ---- GAT layer 1 (in dim 64) ----
    k_wcast2<<<CDIV(512 * 64, 256), 256, 0, stream>>>(g1_wl, g1_wr, g1_bl, g1_br, Wt, bias2, 64, 6);
    k_gemm_mfma<<<ggrid, 256, 0, stream>>>(Hb, Wt, bias2, XL, XR, N, 64);
    k_conv<<<CDIV(N, 4), 256, 0, stream>>>(XL, XR, g1_we, g1_att, csr_src, csr_ea, off,
                                           g1_bias, C, Hb, N);

    // ---- GAT layer 2 (in dim 256) ----
    k_wcast2<<<CDIV(512 * 256, 256), 256, 0, stream>>>(g2_wl, g2_wr, g2_bl, g2_br, Wt, bias2, 256, 8);
    k_gemm_mfma<<<ggrid, 256, 0, stream>>>(Hb, Wt, bias2, XL, XR, N, 256);
    k_conv<<<CDIV(N, 4), 256, 0, stream>>>(XL, XR, g2_we, g2_att, csr_src, csr_ea, off,
                                           g2_bias, C, Hb, N);

    // ---- pool + MLP ----
    k_pool<<<CDIV(N, 64), 256, 0, stream>>>(C, batch, gsum, gcnt, N);
    k_mlp<<<32, 128, 0, stream>>>(gsum, gcnt, p1_w, p1_b, ln_g, ln_b, p2_w, p2_b, out);
}

// Round 4
// 605.338 us; speedup vs baseline: 2.4553x; 1.1716x over previous
//
#include <hip/hip_runtime.h>

#define CDIV(a,b) (((a)+(b)-1)/(b))

typedef __bf16 bf16_t;
typedef bf16_t bf16x8 __attribute__((ext_vector_type(8)));
typedef bf16_t bf16x4 __attribute__((ext_vector_type(4)));
typedef float floatx4 __attribute__((ext_vector_type(4)));

// ---------------------------------------------------------------------------
// K1: per-original-edge degree count + edge_attr sum (for self-loop fill)
__global__ void k_deg(const int* __restrict__ ei, const float* __restrict__ ea,
                      float* __restrict__ deg, float* __restrict__ lsum, int E) {
    int e = blockIdx.x * 256 + threadIdx.x;
    if (e >= E) return;
    int d = ei[E + e];
    atomicAdd(&deg[d], 1.0f);
    atomicAdd(&lsum[d], ea[e]);
}

// K2: loop_attr[n] = lsum[n] / max(deg[n], 1)   (in place on lsum)
__global__ void k_loopattr(float* __restrict__ lsum, const float* __restrict__ deg, int n) {
    int i = blockIdx.x * 256 + threadIdx.x;
    if (i >= n) return;
    lsum[i] = lsum[i] / fmaxf(deg[i], 1.0f);
}

// K3: exclusive scan of (deg[n]+1) -> off[0..n], single block of 1024 threads
__global__ void k_scan(const float* __restrict__ deg, int* __restrict__ off, int n) {
    __shared__ int part[1024];
    int t = threadIdx.x;
    int chunk = (n + 1023) / 1024;
    int s0 = t * chunk;
    int s1 = s0 + chunk; if (s1 > n) s1 = n; if (s0 > n) s0 = n;
    int s = 0;
    for (int i = s0; i < s1; ++i) s += (int)deg[i] + 1;
    part[t] = s;
    __syncthreads();
    for (int d = 1; d < 1024; d <<= 1) {
        int v = (t >= d) ? part[t - d] : 0;
        __syncthreads();
        part[t] += v;
        __syncthreads();
    }
    int excl = (t == 0) ? 0 : part[t - 1];
    for (int i = s0; i < s1; ++i) { off[i] = excl; excl += (int)deg[i] + 1; }
    if (t == 1023) off[n] = excl;
}

// K4: CSR fill over extended edges (E originals + n self loops)
__global__ void k_fill(const int* __restrict__ ei, const float* __restrict__ ea,
                       const float* __restrict__ lattr, const int* __restrict__ off,
                       int* __restrict__ cursor, int* __restrict__ csr_src,
                       float* __restrict__ csr_ea, int E, int n) {
    int e = blockIdx.x * 256 + threadIdx.x;
    int EE = E + n;
    if (e >= EE) return;
    int s, d; float a;
    if (e < E) { s = ei[e]; d = ei[E + e]; a = ea[e]; }
    else       { s = e - E; d = s;         a = lattr[s]; }
    int pos = off[d] + atomicAdd(&cursor[d], 1);
    csr_src[pos] = s;
    csr_ea[pos] = a;
}

// K5: encoder  h0b[n,64] = bf16(relu(x[n,:4] @ enc_w + enc_b))
__global__ void k_enc(const float* __restrict__ x, const float* __restrict__ w,
                      const float* __restrict__ b, bf16_t* __restrict__ h0, int n) {
    int idx = blockIdx.x * 256 + threadIdx.x;
    if (idx >= n * 64) return;
    int nn = idx >> 6, j = idx & 63;
    const float* xr = x + (size_t)nn * 4;
    float s = b[j];
#pragma unroll
    for (int k = 0; k < 4; ++k) s = fmaf(xr[k], w[k * 64 + j], s);
    h0[idx] = (bf16_t)fmaxf(s, 0.0f);
}

// K5c: combined weight transpose+cast  Wl,Wr[K,256] fp32 -> Wt[512,K] bf16
__global__ void k_wcast2(const float* __restrict__ Wl, const float* __restrict__ Wr,
                         const float* __restrict__ bl, const float* __restrict__ br,
                         bf16_t* __restrict__ Wt, float* __restrict__ bias2,
                         int K, int kshift) {
    int idx = blockIdx.x * 256 + threadIdx.x;
    if (idx < 512) bias2[idx] = (idx < 256) ? bl[idx] : br[idx - 256];
    if (idx >= 512 * K) return;
    int nn = idx >> kshift, k = idx & (K - 1);
    float v = (nn < 256) ? Wl[k * 256 + nn] : Wr[k * 256 + (nn - 256)];
    Wt[idx] = (bf16_t)v;
}

// K6: MFMA bf16 GEMM:  [XL|XR][r, :] = Hb[r,:K] @ Wt^T + bias  (bf16 out)
// 128x128 tile, BK=32, 4 waves, 16x16x32 mfma.  LDS: 64B rows, 16B chunks
// XOR-swizzled by (q + (r>>1))&3 -> conflict-free b128 reads & writes.
__global__ __launch_bounds__(256) void k_gemm_mfma(
        const bf16_t* __restrict__ Hb, const bf16_t* __restrict__ Wt,
        const float* __restrict__ bias2, bf16_t* __restrict__ XL,
        bf16_t* __restrict__ XR, int nrows, int K) {
    __shared__ bf16_t As[128 * 32];
    __shared__ bf16_t Bs[128 * 32];
    int tid = threadIdx.x;
    int w = tid >> 6, lane = tid & 63;
    int quad = lane >> 4, m = lane & 15;
    int row0 = blockIdx.x * 128;
    int n0 = blockIdx.y * 128;
    floatx4 acc[2][8];
#pragma unroll
    for (int rt = 0; rt < 2; ++rt)
#pragma unroll
        for (int ct = 0; ct < 8; ++ct)
            acc[rt][ct] = (floatx4){0.f, 0.f, 0.f, 0.f};

    for (int k0 = 0; k0 < K; k0 += 32) {
        __syncthreads();
#pragma unroll
        for (int i = 0; i < 2; ++i) {          // stage A: 128 rows x 32 k
            int c = tid + i * 256;
            int r = c >> 2, kc = c & 3;
            int sw = (kc + (r >> 1)) & 3;
            int gr = row0 + r; if (gr >= nrows) gr = nrows - 1;
            bf16x8 v = *(const bf16x8*)&Hb[(size_t)gr * K + k0 + kc * 8];
            *(bf16x8*)&As[r * 32 + sw * 8] = v;
        }
#pragma unroll
        for (int i = 0; i < 2; ++i) {          // stage B: 128 cols x 32 k
            int c = tid + i * 256;
            int r = c >> 2, kc = c & 3;
            int sw = (kc + (r >> 1)) & 3;
            bf16x8 v = *(const bf16x8*)&Wt[(size_t)(n0 + r) * K + k0 + kc * 8];
            *(bf16x8*)&Bs[r * 32 + sw * 8] = v;
        }
        __syncthreads();
        bf16x8 af[2], bfr[8];
#pragma unroll
        for (int rt = 0; rt < 2; ++rt) {
            int ar = w * 32 + rt * 16 + m;
            af[rt] = *(bf16x8*)&As[ar * 32 + (((quad + (ar >> 1)) & 3) * 8)];
        }
#pragma unroll
        for (int ct = 0; ct < 8; ++ct) {
            int br = ct * 16 + m;
            bfr[ct] = *(bf16x8*)&Bs[br * 32 + (((quad + (br >> 1)) & 3) * 8)];
        }
#pragma unroll
        for (int ct = 0; ct < 8; ++ct) {
            acc[0][ct] = __builtin_amdgcn_mfma_f32_16x16x32_bf16(af[0], bfr[ct], acc[0][ct], 0, 0, 0);
            acc[1][ct] = __builtin_amdgcn_mfma_f32_16x16x32_bf16(af[1], bfr[ct], acc[1][ct], 0, 0, 0);
        }
    }
#pragma unroll
    for (int ct = 0; ct < 8; ++ct) {
        int col = n0 + ct * 16 + m;
        float bv = bias2[col];
        bf16_t* dst = (col < 256) ? XL : XR;
        int c2 = col & 255;
#pragma unroll
        for (int rt = 0; rt < 2; ++rt) {
#pragma unroll
            for (int i = 0; i < 4; ++i) {
                int row = row0 + w * 32 + rt * 16 + quad * 4 + i;
                if (row < nrows) dst[(size_t)row * 256 + c2] = (bf16_t)(acc[rt][ct][i] + bv);
            }
        }
    }
}

// K7: fused GATv2 conv — non-online softmax (alpha bounded -> raw exp safe),
// base-2 exp, LRELU = fmax(t, 0.2t), unroll-2.  One wave per dst node; lane
// covers hc = 4*lane..4*lane+3 (head = lane>>4).
__device__ __forceinline__ void edge_step(
        int p, const int* __restrict__ csr_src, const float* __restrict__ csr_ea,
        const bf16_t* __restrict__ XL, int lane4,
        float xr0, float xr1, float xr2, float xr3,
        const float4& wv, const float4& av,
        float& s, float& a0, float& a1, float& a2, float& a3) {
    int src = csr_src[p];
    float eav = csr_ea[p];
    bf16x4 xlb = *(const bf16x4*)&XL[(size_t)src * 256 + lane4];
    float x0 = (float)xlb.x, x1 = (float)xlb.y, x2 = (float)xlb.z, x3 = (float)xlb.w;
    float t0 = fmaf(eav, wv.x, x0 + xr0); t0 = fmaxf(t0, 0.2f * t0);
    float t1 = fmaf(eav, wv.y, x1 + xr1); t1 = fmaxf(t1, 0.2f * t1);
    float t2 = fmaf(eav, wv.z, x2 + xr2); t2 = fmaxf(t2, 0.2f * t2);
    float t3 = fmaf(eav, wv.w, x3 + xr3); t3 = fmaxf(t3, 0.2f * t3);
    float al = fmaf(t3, av.w, fmaf(t2, av.z, fmaf(t1, av.y, t0 * av.x)));
    al += __shfl_xor(al, 1, 16);
    al += __shfl_xor(al, 2, 16);
    al += __shfl_xor(al, 4, 16);
    al += __shfl_xor(al, 8, 16);
    float wg = exp2f(al);          // av pre-scaled by 1/ln2 -> wg = e^alpha
    s += wg;
    a0 = fmaf(wg, x0, a0);
    a1 = fmaf(wg, x1, a1);
    a2 = fmaf(wg, x2, a2);
    a3 = fmaf(wg, x3, a3);
}

__global__ void k_conv(const bf16_t* __restrict__ XL, const bf16_t* __restrict__ XR,
                       const float* __restrict__ we, const float* __restrict__ att,
                       const int* __restrict__ csr_src, const float* __restrict__ csr_ea,
                       const int* __restrict__ off, const float* __restrict__ bias,
                       float* __restrict__ outf, bf16_t* __restrict__ outb, int n) {
    int wid = (blockIdx.x * 256 + threadIdx.x) >> 6;
    int lane = threadIdx.x & 63;
    if (wid >= n) return;
    int lane4 = lane * 4;
    bf16x4 xrb = *(const bf16x4*)&XR[(size_t)wid * 256 + lane4];
    float xr0 = (float)xrb.x, xr1 = (float)xrb.y, xr2 = (float)xrb.z, xr3 = (float)xrb.w;
    float4 wv = ((const float4*)we)[lane];
    float4 av = ((const float4*)att)[lane];
    av.x *= 1.44269504f; av.y *= 1.44269504f; av.z *= 1.44269504f; av.w *= 1.44269504f;
    int p0 = off[wid], p1 = off[wid + 1];
    float s = 0.f, a0 = 0.f, a1 = 0.f, a2 = 0.f, a3 = 0.f;
    int p = p0;
    for (; p + 1 < p1; p += 2) {
        edge_step(p,     csr_src, csr_ea, XL, lane4, xr0, xr1, xr2, xr3, wv, av, s, a0, a1, a2, a3);
        edge_step(p + 1, csr_src, csr_ea, XL, lane4, xr0, xr1, xr2, xr3, wv, av, s, a0, a1, a2, a3);
    }
    if (p < p1)
        edge_step(p,     csr_src, csr_ea, XL, lane4, xr0, xr1, xr2, xr3, wv, av, s, a0, a1, a2, a3);
    float inv = 1.0f / s;
    float4 bv = ((const float4*)bias)[lane];
    float o0 = fmaxf(fmaf(a0, inv, bv.x), 0.f);
    float o1 = fmaxf(fmaf(a1, inv, bv.y), 0.f);
    float o2 = fmaxf(fmaf(a2, inv, bv.z), 0.f);
    float o3 = fmaxf(fmaf(a3, inv, bv.w), 0.f);
    if (outf)
        ((float4*)outf)[(size_t)wid * 64 + lane] = (float4){o0, o1, o2, o3};
    if (outb) {
        bf16x4 ob;
        ob.x = (bf16_t)o0; ob.y = (bf16_t)o1; ob.z = (bf16_t)o2; ob.w = (bf16_t)o3;
        *(bf16x4*)&outb[(size_t)wid * 256 + lane4] = ob;
    }
}

// K9: global mean pool.  batch sorted; 64-node chunks -> ~800 blocks.
__global__ void k_pool(const float* __restrict__ h, const int* __restrict__ batch,
                       float* __restrict__ gsum, float* __restrict__ gcnt, int n) {
    int j = threadIdx.x;
    int start = blockIdx.x * 64;
    if (start >= n) return;
    int end = start + 64; if (end > n) end = n;
    int cur = batch[start];
    float acc = 0.0f, cnt = 0.0f;
    for (int i = start; i < end; ++i) {
        int g = batch[i];
        if (g != cur) {
            atomicAdd(&gsum[cur * 256 + j], acc);
            if (j == 0) atomicAdd(&gcnt[cur], cnt);
            acc = 0.0f; cnt = 0.0f; cur = g;
        }
        acc += h[(size_t)i * 256 + j];
        cnt += 1.0f;
    }
    atomicAdd(&gsum[cur * 256 + j], acc);
    if (j == 0) atomicAdd(&gcnt[cur], cnt);
}

// K10: post MLP: 256->128, LayerNorm, relu, 128->64, relu.  1 block per graph.
__global__ void k_mlp(const float* __restrict__ gsum, const float* __restrict__ gcnt,
                      const float* __restrict__ p1w, const float* __restrict__ p1b,
                      const float* __restrict__ lng, const float* __restrict__ lnb,
                      const float* __restrict__ p2w, const float* __restrict__ p2b,
                      float* __restrict__ out) {
    int g = blockIdx.x;
    int t = threadIdx.x; // 128
    __shared__ float gv[256];
    __shared__ float z[128];
    __shared__ float red[128];
    float invc = 1.0f / fmaxf(gcnt[g], 1.0f);
    gv[t]       = gsum[g * 256 + t] * invc;
    gv[t + 128] = gsum[g * 256 + 128 + t] * invc;
    __syncthreads();
    float z1 = p1b[t];
    for (int k = 0; k < 256; ++k) z1 = fmaf(gv[k], p1w[k * 128 + t], z1);
    red[t] = z1;
    __syncthreads();
    for (int d = 64; d > 0; d >>= 1) { if (t < d) red[t] += red[t + d]; __syncthreads(); }
    float mu = red[0] * (1.0f / 128.0f);
    __syncthreads();
    float dz = z1 - mu;
    red[t] = dz * dz;
    __syncthreads();
    for (int d = 64; d > 0; d >>= 1) { if (t < d) red[t] += red[t + d]; __syncthreads(); }
    float var = red[0] * (1.0f / 128.0f);
    float zn = dz * rsqrtf(var + 1e-5f) * lng[t] + lnb[t];
    z[t] = fmaxf(zn, 0.0f);
    __syncthreads();
    if (t < 64) {
        float o = p2b[t];
        for (int k = 0; k < 128; ++k) o = fmaf(z[k], p2w[k * 64 + t], o);
        out[g * 64 + t] = fmaxf(o, 0.0f);
    }
}

extern "C" void kernel_launch(void* const* d_in, const int* in_sizes, int n_in,
                              void* d_out, int out_size, void* d_ws, size_t ws_size,
                              hipStream_t stream) {
    const float* x      = (const float*)d_in[0];
    const int*   ei     = (const int*)d_in[1];
    const float* ea     = (const float*)d_in[2];
    const int*   batch  = (const int*)d_in[3];
    const float* enc_w  = (const float*)d_in[4];
    const float* enc_b  = (const float*)d_in[5];
    const float* g1_wl  = (const float*)d_in[6];
    const float* g1_bl  = (const float*)d_in[7];
    const float* g1_wr  = (const float*)d_in[8];
    const float* g1_br  = (const float*)d_in[9];
    const float* g1_we  = (const float*)d_in[10];
    const float* g1_att = (const float*)d_in[11];
    const float* g1_bias= (const float*)d_in[12];
    const float* g2_wl  = (const float*)d_in[13];
    const float* g2_bl  = (const float*)d_in[14];
    const float* g2_wr  = (const float*)d_in[15];
    const float* g2_br  = (const float*)d_in[16];
    const float* g2_we  = (const float*)d_in[17];
    const float* g2_att = (const float*)d_in[18];
    const float* g2_bias= (const float*)d_in[19];
    const float* p1_w   = (const float*)d_in[20];
    const float* p1_b   = (const float*)d_in[21];
    const float* ln_g   = (const float*)d_in[22];
    const float* ln_b   = (const float*)d_in[23];
    const float* p2_w   = (const float*)d_in[24];
    const float* p2_b   = (const float*)d_in[25];
    float* out = (float*)d_out;

    const int N  = in_sizes[3];
    const int E  = in_sizes[1] / 2;
    const int EE = E + N;

    // workspace carve (bf16 buffers first for 16B alignment)
    bf16_t* XL  = (bf16_t*)d_ws;               // [N,256] bf16
    bf16_t* XR  = XL + (size_t)N * 256;        // [N,256] bf16
    bf16_t* Hb  = XR + (size_t)N * 256;        // [N,256] bf16 (layer1 uses [N,64])
    bf16_t* Wt  = Hb + (size_t)N * 256;        // [512,256] bf16
    float* C     = (float*)(Wt + 512 * 256);   // layer-2 out (fp32, for pool) [N,256]
    float* csr_ea= C + (size_t)N * 256;        // [EE]
    float* bias2 = csr_ea + EE;                // [512]
    float* deg   = bias2 + 512;                // [N]   -- zeroed region start
    float* lsum  = deg + N;                    // [N]
    float* gsum  = lsum + N;                   // [32*256]
    float* gcnt  = gsum + 32 * 256;            // [32]
    int*   cursor= (int*)(gcnt + 32);          // [N]   -- zeroed region end
    int*   off   = cursor + N;                 // [N+1]
    int*   csr_src = off + (N + 1);            // [EE]

    hipMemsetAsync(deg, 0, (size_t)(3 * N + 32 * 256 + 32) * sizeof(float), stream);

    k_deg<<<CDIV(E, 256), 256, 0, stream>>>(ei, ea, deg, lsum, E);
    k_loopattr<<<CDIV(N, 256), 256, 0, stream>>>(lsum, deg, N);
    k_scan<<<1, 1024, 0, stream>>>(deg, off, N);
    k_fill<<<CDIV(EE, 256), 256, 0, stream>>>(ei, ea, lsum, off, cursor, csr_src, csr_ea, E, N);
    k_enc<<<CDIV(N * 64, 256), 256, 0, stream>>>(x, enc_w, enc_b, Hb, N);

    dim3 ggrid(CDIV(N, 128), 4);   // 4 col-tiles = 512 output cols (XL|XR)

    // ---- GAT layer 1 (in dim 64) ----
    k_wcast2<<<CDIV(512 * 64, 256), 256, 0, stream>>>(g1_wl, g1_wr, g1_bl, g1_br, Wt, bias2, 64, 6);
    k_gemm_mfma<<<ggrid, 256, 0, stream>>>(Hb, Wt, bias2, XL, XR, N, 64);
    k_conv<<<CDIV(N, 4), 256, 0, stream>>>(XL, XR, g1_we, g1_att, csr_src, csr_ea, off,
                                           g1_bias, nullptr, Hb, N);

    // ---- GAT layer 2 (in dim 256) ----
    k_wcast2<<<CDIV(512 * 256, 256), 256, 0, stream>>>(g2_wl, g2_wr, g2_bl, g2_br, Wt, bias2, 256, 8);
    k_gemm_mfma<<<ggrid, 256, 0, stream>>>(Hb, Wt, bias2, XL, XR, N, 256);
    k_conv<<<CDIV(N, 4), 256, 0, stream>>>(XL, XR, g2_we, g2_att, csr_src, csr_ea, off,
                                           g2_bias, C, nullptr, N);

    // ---- pool + MLP ----
    k_pool<<<CDIV(N, 64), 256, 0, stream>>>(C, batch, gsum, gcnt, N);
    k_mlp<<<32, 128, 0, stream>>>(gsum, gcnt, p1_w, p1_b, ln_g, ln_b, p2_w, p2_b, out);
}

// Round 5
// 510.851 us; speedup vs baseline: 2.9094x; 1.1850x over previous
//
#include <hip/hip_runtime.h>

#define CDIV(a,b) (((a)+(b)-1)/(b))

typedef __bf16 bf16_t;
typedef bf16_t bf16x8 __attribute__((ext_vector_type(8)));
typedef bf16_t bf16x4 __attribute__((ext_vector_type(4)));
typedef float floatx4 __attribute__((ext_vector_type(4)));
typedef float floatx2 __attribute__((ext_vector_type(2)));

// sigma: storage position p -> original feature index (within 256)
__device__ __forceinline__ int sigma(int p) {
    return ((p >> 7) << 7) + ((p & 7) << 4) + ((p >> 3) & 15);
}

// ---------------------------------------------------------------------------
// K1: per-original-edge degree count + edge_attr sum (for self-loop fill)
__global__ void k_deg(const int* __restrict__ ei, const float* __restrict__ ea,
                      float* __restrict__ deg, float* __restrict__ lsum, int E) {
    int e = blockIdx.x * 256 + threadIdx.x;
    if (e >= E) return;
    int d = ei[E + e];
    atomicAdd(&deg[d], 1.0f);
    atomicAdd(&lsum[d], ea[e]);
}

// K2: loop_attr[n] = lsum[n] / max(deg[n], 1)   (in place on lsum)
__global__ void k_loopattr(float* __restrict__ lsum, const float* __restrict__ deg, int n) {
    int i = blockIdx.x * 256 + threadIdx.x;
    if (i >= n) return;
    lsum[i] = lsum[i] / fmaxf(deg[i], 1.0f);
}

// K3: parallel exclusive scan of (deg[i]+1) -> off[0..n], 3 phases.
__global__ void k_scanA(const float* __restrict__ deg, int* __restrict__ part, int n) {
    __shared__ int sh[256];
    int t = threadIdx.x;
    int i = blockIdx.x * 256 + t;
    int v = (i < n) ? (int)deg[i] + 1 : 0;
    sh[t] = v;
    __syncthreads();
    for (int d = 128; d > 0; d >>= 1) { if (t < d) sh[t] += sh[t + d]; __syncthreads(); }
    if (t == 0) part[blockIdx.x] = sh[0];
}
__global__ void k_scanB(int* __restrict__ part, int nb) {
    __shared__ int sh[256];
    int t = threadIdx.x;
    int v = (t < nb) ? part[t] : 0;
    sh[t] = v;
    __syncthreads();
    for (int d = 1; d < 256; d <<= 1) {
        int u = (t >= d) ? sh[t - d] : 0;
        __syncthreads();
        sh[t] += u;
        __syncthreads();
    }
    if (t < nb) part[t] = sh[t] - v;   // exclusive
}
__global__ void k_scanC(const float* __restrict__ deg, const int* __restrict__ part,
                        int* __restrict__ off, int n) {
    __shared__ int sh[256];
    int t = threadIdx.x;
    int i = blockIdx.x * 256 + t;
    int v = (i < n) ? (int)deg[i] + 1 : 0;
    sh[t] = v;
    __syncthreads();
    for (int d = 1; d < 256; d <<= 1) {
        int u = (t >= d) ? sh[t - d] : 0;
        __syncthreads();
        sh[t] += u;
        __syncthreads();
    }
    int excl = part[blockIdx.x] + sh[t] - v;
    if (i < n) off[i] = excl;
    if (i == n - 1) off[n] = excl + v;
}

// K4: CSR fill over extended edges (E originals + n self loops)
__global__ void k_fill(const int* __restrict__ ei, const float* __restrict__ ea,
                       const float* __restrict__ lattr, const int* __restrict__ off,
                       int* __restrict__ cursor, int* __restrict__ csr_src,
                       float* __restrict__ csr_ea, int E, int n) {
    int e = blockIdx.x * 256 + threadIdx.x;
    int EE = E + n;
    if (e >= EE) return;
    int s, d; float a;
    if (e < E) { s = ei[e]; d = ei[E + e]; a = ea[e]; }
    else       { s = e - E; d = s;         a = lattr[s]; }
    int pos = off[d] + atomicAdd(&cursor[d], 1);
    csr_src[pos] = s;
    csr_ea[pos] = a;
}

// K5: encoder  h0b[n,64] = bf16(relu(x[n,:4] @ enc_w + enc_b))
__global__ void k_enc(const float* __restrict__ x, const float* __restrict__ w,
                      const float* __restrict__ b, bf16_t* __restrict__ h0, int n) {
    int idx = blockIdx.x * 256 + threadIdx.x;
    if (idx >= n * 64) return;
    int nn = idx >> 6, j = idx & 63;
    const float* xr = x + (size_t)nn * 4;
    float s = b[j];
#pragma unroll
    for (int k = 0; k < 4; ++k) s = fmaf(xr[k], w[k * 64 + j], s);
    h0[idx] = (bf16_t)fmaxf(s, 0.0f);
}

// K5c: combined weight transpose+cast Wl,Wr[K,256] fp32 -> Wt[512,K] bf16.
// permK: layer-2 A (Hb) is in sigma layout -> permute Wt's K dim to match.
// Also emits sigma-permuted copies of we/att/conv-bias for k_conv.
__global__ void k_wcast2(const float* __restrict__ Wl, const float* __restrict__ Wr,
                         const float* __restrict__ bl, const float* __restrict__ br,
                         bf16_t* __restrict__ Wt, float* __restrict__ bias2,
                         int K, int kshift, int permK,
                         const float* __restrict__ we, const float* __restrict__ att,
                         const float* __restrict__ cb,
                         float* __restrict__ wep, float* __restrict__ attp,
                         float* __restrict__ cbp) {
    int idx = blockIdx.x * 256 + threadIdx.x;
    if (idx < 512) bias2[idx] = (idx < 256) ? bl[idx] : br[idx - 256];
    if (idx < 256) {
        int sg = sigma(idx);
        wep[idx] = we[sg]; attp[idx] = att[sg]; cbp[idx] = cb[sg];
    }
    if (idx >= 512 * K) return;
    int nn = idx >> kshift, k = idx & (K - 1);
    int ks = permK ? sigma(k) : k;
    float v = (nn < 256) ? Wl[ks * 256 + nn] : Wr[ks * 256 + (nn - 256)];
    Wt[idx] = (bf16_t)v;
}

// K6: MFMA bf16 GEMM:  [XL|XR] = Hb @ Wt^T + bias, output rows stored in
// sigma layout (pos = tile*128 + m*8 + ct) -> per-thread bf16x8 coalesced
// stores.  128x128 tile, BK=32, 4 waves, 16x16x32 mfma.  LDS: 64B rows,
// 16B chunks XOR-swizzled by (q + (r>>1))&3 -> conflict-free b128 r/w.
__global__ __launch_bounds__(256) void k_gemm_mfma(
        const bf16_t* __restrict__ Hb, const bf16_t* __restrict__ Wt,
        const float* __restrict__ bias2, bf16_t* __restrict__ XL,
        bf16_t* __restrict__ XR, int nrows, int K) {
    __shared__ bf16_t As[128 * 32];
    __shared__ bf16_t Bs[128 * 32];
    int tid = threadIdx.x;
    int w = tid >> 6, lane = tid & 63;
    int quad = lane >> 4, m = lane & 15;
    int row0 = blockIdx.x * 128;
    int n0 = blockIdx.y * 128;
    floatx4 acc[2][8];
#pragma unroll
    for (int rt = 0; rt < 2; ++rt)
#pragma unroll
        for (int ct = 0; ct < 8; ++ct)
            acc[rt][ct] = (floatx4){0.f, 0.f, 0.f, 0.f};

    for (int k0 = 0; k0 < K; k0 += 32) {
        __syncthreads();
#pragma unroll
        for (int i = 0; i < 2; ++i) {          // stage A: 128 rows x 32 k
            int c = tid + i * 256;
            int r = c >> 2, kc = c & 3;
            int sw = (kc + (r >> 1)) & 3;
            int gr = row0 + r; if (gr >= nrows) gr = nrows - 1;
            bf16x8 v = *(const bf16x8*)&Hb[(size_t)gr * K + k0 + kc * 8];
            *(bf16x8*)&As[r * 32 + sw * 8] = v;
        }
#pragma unroll
        for (int i = 0; i < 2; ++i) {          // stage B: 128 cols x 32 k
            int c = tid + i * 256;
            int r = c >> 2, kc = c & 3;
            int sw = (kc + (r >> 1)) & 3;
            bf16x8 v = *(const bf16x8*)&Wt[(size_t)(n0 + r) * K + k0 + kc * 8];
            *(bf16x8*)&Bs[r * 32 + sw * 8] = v;
        }
        __syncthreads();
        bf16x8 af[2], bfr[8];
#pragma unroll
        for (int rt = 0; rt < 2; ++rt) {
            int ar = w * 32 + rt * 16 + m;
            af[rt] = *(bf16x8*)&As[ar * 32 + (((quad + (ar >> 1)) & 3) * 8)];
        }
#pragma unroll
        for (int ct = 0; ct < 8; ++ct) {
            int br = ct * 16 + m;
            bfr[ct] = *(bf16x8*)&Bs[br * 32 + (((quad + (br >> 1)) & 3) * 8)];
        }
#pragma unroll
        for (int ct = 0; ct < 8; ++ct) {
            acc[0][ct] = __builtin_amdgcn_mfma_f32_16x16x32_bf16(af[0], bfr[ct], acc[0][ct], 0, 0, 0);
            acc[1][ct] = __builtin_amdgcn_mfma_f32_16x16x32_bf16(af[1], bfr[ct], acc[1][ct], 0, 0, 0);
        }
    }
    // epilogue: sigma-layout coalesced stores (16B per thread per row)
    int tile = (n0 >> 7) & 1;
    bf16_t* dst = (n0 < 256) ? XL : XR;
    float bv[8];
#pragma unroll
    for (int ct = 0; ct < 8; ++ct) bv[ct] = bias2[n0 + ct * 16 + m];
#pragma unroll
    for (int rt = 0; rt < 2; ++rt) {
#pragma unroll
        for (int i = 0; i < 4; ++i) {
            int row = row0 + w * 32 + rt * 16 + quad * 4 + i;
            if (row < nrows) {
                bf16x8 v;
#pragma unroll
                for (int ct = 0; ct < 8; ++ct) v[ct] = (bf16_t)(acc[rt][ct][i] + bv[ct]);
                *(bf16x8*)&dst[(size_t)row * 256 + tile * 128 + m * 8] = v;
            }
        }
    }
}

// K7: fused GATv2 conv, sigma layout.  One wave per dst node; lane L covers
// positions 4L..4L+3 (head = (L>>5)*2 + (L&1)); packed fp32 math.
__device__ __forceinline__ void edge_step(
        int p, const int* __restrict__ csr_src, const float* __restrict__ csr_ea,
        const bf16_t* __restrict__ XL, int lane8,
        floatx2 xr01, floatx2 xr23, floatx2 wv01, floatx2 wv23,
        floatx2 av01, floatx2 av23,
        float& s, floatx2& a01, floatx2& a23) {
    int src = csr_src[p];
    float eav = csr_ea[p];
    uint2 u = *(const uint2*)((const char*)XL + (size_t)src * 512 + lane8);
    floatx2 x01, x23;
    x01.x = __uint_as_float(u.x << 16);
    x01.y = __uint_as_float(u.x & 0xffff0000u);
    x23.x = __uint_as_float(u.y << 16);
    x23.y = __uint_as_float(u.y & 0xffff0000u);
    floatx2 t01 = x01 + xr01 + eav * wv01;
    floatx2 t23 = x23 + xr23 + eav * wv23;
    t01 = __builtin_elementwise_max(t01, 0.2f * t01);
    t23 = __builtin_elementwise_max(t23, 0.2f * t23);
    floatx2 d = t01 * av01 + t23 * av23;
    float al = d.x + d.y;
    al += __shfl_xor(al, 2);
    al += __shfl_xor(al, 4);
    al += __shfl_xor(al, 8);
    al += __shfl_xor(al, 16);
    float wg = exp2f(al);          // att pre-scaled by 1/ln2 -> wg = e^alpha
    s += wg;
    a01 += wg * x01;
    a23 += wg * x23;
}

__global__ void k_conv(const bf16_t* __restrict__ XL, const bf16_t* __restrict__ XR,
                       const float* __restrict__ wep, const float* __restrict__ attp,
                       const int* __restrict__ csr_src, const float* __restrict__ csr_ea,
                       const int* __restrict__ off, const float* __restrict__ cbp,
                       bf16_t* __restrict__ outb, int n) {
    int wid = (blockIdx.x * 256 + threadIdx.x) >> 6;
    int lane = threadIdx.x & 63;
    if (wid >= n) return;
    int lane8 = lane * 8;
    uint2 ur = *(const uint2*)((const char*)XR + (size_t)wid * 512 + lane8);
    floatx2 xr01, xr23;
    xr01.x = __uint_as_float(ur.x << 16);
    xr01.y = __uint_as_float(ur.x & 0xffff0000u);
    xr23.x = __uint_as_float(ur.y << 16);
    xr23.y = __uint_as_float(ur.y & 0xffff0000u);
    float4 wv = ((const float4*)wep)[lane];
    float4 av = ((const float4*)attp)[lane];
    floatx2 wv01 = {wv.x, wv.y}, wv23 = {wv.z, wv.w};
    floatx2 av01 = {av.x * 1.44269504f, av.y * 1.44269504f};
    floatx2 av23 = {av.z * 1.44269504f, av.w * 1.44269504f};
    int p0 = off[wid], p1 = off[wid + 1];
    float s = 0.f;
    floatx2 a01 = {0.f, 0.f}, a23 = {0.f, 0.f};
    int p = p0;
    for (; p + 1 < p1; p += 2) {
        edge_step(p,     csr_src, csr_ea, XL, lane8, xr01, xr23, wv01, wv23, av01, av23, s, a01, a23);
        edge_step(p + 1, csr_src, csr_ea, XL, lane8, xr01, xr23, wv01, wv23, av01, av23, s, a01, a23);
    }
    if (p < p1)
        edge_step(p,     csr_src, csr_ea, XL, lane8, xr01, xr23, wv01, wv23, av01, av23, s, a01, a23);
    float inv = 1.0f / s;
    float4 bv = ((const float4*)cbp)[lane];
    float o0 = fmaxf(fmaf(a01.x, inv, bv.x), 0.f);
    float o1 = fmaxf(fmaf(a01.y, inv, bv.y), 0.f);
    float o2 = fmaxf(fmaf(a23.x, inv, bv.z), 0.f);
    float o3 = fmaxf(fmaf(a23.y, inv, bv.w), 0.f);
    bf16x4 ob;
    ob.x = (bf16_t)o0; ob.y = (bf16_t)o1; ob.z = (bf16_t)o2; ob.w = (bf16_t)o3;
    *(bf16x4*)&outb[(size_t)wid * 256 + lane * 4] = ob;
}

// K9: global mean pool on bf16 input (sigma order preserved in gsum).
__global__ void k_pool(const bf16_t* __restrict__ h, const int* __restrict__ batch,
                       float* __restrict__ gsum, float* __restrict__ gcnt, int n) {
    int j = threadIdx.x;
    int start = blockIdx.x * 64;
    if (start >= n) return;
    int end = start + 64; if (end > n) end = n;
    int cur = batch[start];
    float acc = 0.0f, cnt = 0.0f;
    for (int i = start; i < end; ++i) {
        int g = batch[i];
        if (g != cur) {
            atomicAdd(&gsum[cur * 256 + j], acc);
            if (j == 0) atomicAdd(&gcnt[cur], cnt);
            acc = 0.0f; cnt = 0.0f; cur = g;
        }
        acc += (float)h[(size_t)i * 256 + j];
        cnt += 1.0f;
    }
    atomicAdd(&gsum[cur * 256 + j], acc);
    if (j == 0) atomicAdd(&gcnt[cur], cnt);
}

// K10: post MLP.  gsum is in sigma order -> un-permute when loading gv.
__global__ void k_mlp(const float* __restrict__ gsum, const float* __restrict__ gcnt,
                      const float* __restrict__ p1w, const float* __restrict__ p1b,
                      const float* __restrict__ lng, const float* __restrict__ lnb,
                      const float* __restrict__ p2w, const float* __restrict__ p2b,
                      float* __restrict__ out) {
    int g = blockIdx.x;
    int t = threadIdx.x; // 128
    __shared__ float gv[256];
    __shared__ float z[128];
    __shared__ float red[128];
    float invc = 1.0f / fmaxf(gcnt[g], 1.0f);
    gv[sigma(t)]       = gsum[g * 256 + t] * invc;
    gv[sigma(t + 128)] = gsum[g * 256 + 128 + t] * invc;
    __syncthreads();
    float z1 = p1b[t];
    for (int k = 0; k < 256; ++k) z1 = fmaf(gv[k], p1w[k * 128 + t], z1);
    red[t] = z1;
    __syncthreads();
    for (int d = 64; d > 0; d >>= 1) { if (t < d) red[t] += red[t + d]; __syncthreads(); }
    float mu = red[0] * (1.0f / 128.0f);
    __syncthreads();
    float dz = z1 - mu;
    red[t] = dz * dz;
    __syncthreads();
    for (int d = 64; d > 0; d >>= 1) { if (t < d) red[t] += red[t + d]; __syncthreads(); }
    float var = red[0] * (1.0f / 128.0f);
    float zn = dz * rsqrtf(var + 1e-5f) * lng[t] + lnb[t];
    z[t] = fmaxf(zn, 0.0f);
    __syncthreads();
    if (t < 64) {
        float o = p2b[t];
        for (int k = 0; k < 128; ++k) o = fmaf(z[k], p2w[k * 64 + t], o);
        out[g * 64 + t] = fmaxf(o, 0.0f);
    }
}

extern "C" void kernel_launch(void* const* d_in, const int* in_sizes, int n_in,
                              void* d_out, int out_size, void* d_ws, size_t ws_size,
                              hipStream_t stream) {
    const float* x      = (const float*)d_in[0];
    const int*   ei     = (const int*)d_in[1];
    const float* ea     = (const float*)d_in[2];
    const int*   batch  = (const int*)d_in[3];
    const float* enc_w  = (const float*)d_in[4];
    const float* enc_b  = (const float*)d_in[5];
    const float* g1_wl  = (const float*)d_in[6];
    const float* g1_bl  = (const float*)d_in[7];
    const float* g1_wr  = (const float*)d_in[8];
    const float* g1_br  = (const float*)d_in[9];
    const float* g1_we  = (const float*)d_in[10];
    const float* g1_att = (const float*)d_in[11];
    const float* g1_bias= (const float*)d_in[12];
    const float* g2_wl  = (const float*)d_in[13];
    const float* g2_bl  = (const float*)d_in[14];
    const float* g2_wr  = (const float*)d_in[15];
    const float* g2_br  = (const float*)d_in[16];
    const float* g2_we  = (const float*)d_in[17];
    const float* g2_att = (const float*)d_in[18];
    const float* g2_bias= (const float*)d_in[19];
    const float* p1_w   = (const float*)d_in[20];
    const float* p1_b   = (const float*)d_in[21];
    const float* ln_g   = (const float*)d_in[22];
    const float* ln_b   = (const float*)d_in[23];
    const float* p2_w   = (const float*)d_in[24];
    const float* p2_b   = (const float*)d_in[25];
    float* out = (float*)d_out;

    const int N  = in_sizes[3];
    const int E  = in_sizes[1] / 2;
    const int EE = E + N;
    const int NB = CDIV(N, 256);

    // workspace carve (bf16 buffers first for 16B alignment)
    bf16_t* XL  = (bf16_t*)d_ws;               // [N,256] bf16 (sigma layout)
    bf16_t* XR  = XL + (size_t)N * 256;        // [N,256] bf16 (sigma layout)
    bf16_t* Hb  = XR + (size_t)N * 256;        // [N,256] bf16 (layer1: [N,64])
    bf16_t* Wt  = Hb + (size_t)N * 256;        // [512,256] bf16
    float* csr_ea= (float*)(Wt + 512 * 256);   // [EE]
    float* bias2 = csr_ea + EE;                // [512]
    float* wep   = bias2 + 512;                // [256]
    float* attp  = wep + 256;                  // [256]
    float* cbp   = attp + 256;                 // [256]
    float* deg   = cbp + 256;                  // [N]   -- zeroed region start
    float* lsum  = deg + N;                    // [N]
    float* gsum  = lsum + N;                   // [32*256]
    float* gcnt  = gsum + 32 * 256;            // [32]
    int*   cursor= (int*)(gcnt + 32);          // [N]   -- zeroed region end
    int*   part  = cursor + N;                 // [256]
    int*   off   = part + 256;                 // [N+1]
    int*   csr_src = off + (N + 1);            // [EE]

    hipMemsetAsync(deg, 0, (size_t)(3 * N + 32 * 256 + 32) * sizeof(float), stream);

    k_deg<<<CDIV(E, 256), 256, 0, stream>>>(ei, ea, deg, lsum, E);
    k_loopattr<<<CDIV(N, 256), 256, 0, stream>>>(lsum, deg, N);
    k_scanA<<<NB, 256, 0, stream>>>(deg, part, N);
    k_scanB<<<1, 256, 0, stream>>>(part, NB);
    k_scanC<<<NB, 256, 0, stream>>>(deg, part, off, N);
    k_fill<<<CDIV(EE, 256), 256, 0, stream>>>(ei, ea, lsum, off, cursor, csr_src, csr_ea, E, N);
    k_enc<<<CDIV(N * 64, 256), 256, 0, stream>>>(x, enc_w, enc_b, Hb, N);

    dim3 ggrid(CDIV(N, 128), 4);   // 4 col-tiles = 512 output cols (XL|XR)

    // ---- GAT layer 1 (in dim 64) ----
    k_wcast2<<<CDIV(512 * 64, 256), 256, 0, stream>>>(g1_wl, g1_wr, g1_bl, g1_br, Wt, bias2,
                                                      64, 6, 0, g1_we, g1_att, g1_bias,
                                                      wep, attp, cbp);
    k_gemm_mfma<<<ggrid, 256, 0, stream>>>(Hb, Wt, bias2, XL, XR, N, 64);
    k_conv<<<CDIV(N, 4), 256, 0, stream>>>(XL, XR, wep, attp, csr_src, csr_ea, off, cbp, Hb, N);

    // ---- GAT layer 2 (in dim 256, K sigma-permuted to match Hb layout) ----
    k_wcast2<<<CDIV(512 * 256, 256), 256, 0, stream>>>(g2_wl, g2_wr, g2_bl, g2_br, Wt, bias2,
                                                       256, 8, 1, g2_we, g2_att, g2_bias,
                                                       wep, attp, cbp);
    k_gemm_mfma<<<ggrid, 256, 0, stream>>>(Hb, Wt, bias2, XL, XR, N, 256);
    k_conv<<<CDIV(N, 4), 256, 0, stream>>>(XL, XR, wep, attp, csr_src, csr_ea, off, cbp, Hb, N);

    // ---- pool + MLP ----
    k_pool<<<CDIV(N, 64), 256, 0, stream>>>(Hb, batch, gsum, gcnt, N);
    k_mlp<<<32, 128, 0, stream>>>(gsum, gcnt, p1_w, p1_b, ln_g, ln_b, p2_w, p2_b, out);
}